// Round 15
// baseline (69.815 us; speedup 1.0000x reference)
//
#include <hip/hip_runtime.h>

#define DD 40
#define SLM1 9
#define ANUM 268
#define MB 32

typedef __attribute__((ext_vector_type(8))) short short8;
typedef __attribute__((ext_vector_type(4))) float f32x4;
typedef __attribute__((ext_vector_type(16))) float f32x16;

// ws offsets (u16 units) -- identical layout to r12/r14
#define WS_LWF ((size_t)0)        // full tiles: (s*40+d)*1536 ; e=0..31
#define WS_LWT ((size_t)552960)   // tail tiles: (s*10+t)*1536 ; col c -> d=4t+(c>>3), e=32+(c&7)
#define WS_QW  ((size_t)691200)   // s*3072 (+ et*1536)
#define WS_MW  ((size_t)718848)   // s*3072
#define WS_TW  ((size_t)746496)   // t*1536

__device__ __forceinline__ unsigned short f2bf(float f){
  unsigned int u = __float_as_uint(f);
  u += 0x7FFFu + ((u >> 16) & 1u);
  return (unsigned short)(u >> 16);
}
__device__ __forceinline__ float relu6f(float v){
  return fminf(fmaxf(v, 0.0f), 6.0f);
}

__device__ __forceinline__ f32x16 mfma3(short8 a0, short8 a1, short8 a2,
                                        short8 b0, short8 b1, short8 b2){
  f32x16 c = {0,0,0,0,0,0,0,0,0,0,0,0,0,0,0,0};
  c = __builtin_amdgcn_mfma_f32_32x32x16_bf16(a0, b0, c, 0, 0, 0);
  c = __builtin_amdgcn_mfma_f32_32x32x16_bf16(a1, b1, c, 0, 0, 0);
  c = __builtin_amdgcn_mfma_f32_32x32x16_bf16(a2, b2, c, 0, 0, 0);
  return c;
}

// Build 32x32x16 MFMA B-fragments with bias rows folded into K-pad slots.
// B layout: col = l&31, k = 8*(l>>5)+j (+16*kf).  (verified r3-r14)
__global__ __launch_bounds__(256)
void prep_frags(const float* __restrict__ Qw, const float* __restrict__ Lw,
                const float* __restrict__ Mw, const float* __restrict__ Tw,
                const float* __restrict__ Ew, const float* __restrict__ Eb,
                const float* __restrict__ Qb, const float* __restrict__ Lb,
                const float* __restrict__ Mb, const float* __restrict__ Tb,
                unsigned short* __restrict__ ws)
{
  const int bid = blockIdx.x, tid = threadIdx.x;
  if (bid < 360){                       // Lw full tiles (e 0..31), one per (s,d)
    int s = bid / 40, d = bid - s*40;
    unsigned short* dst = ws + WS_LWF + (size_t)bid*1536;
    const float* W = Lw + (size_t)s*64000;
    const float* bv = Lb + (size_t)s*1600;
    for (int i = tid; i < 1536; i += 256){
      int kf = i >> 9, q = i & 511, l = q >> 3, j = q & 7;
      int k = kf*16 + ((l >> 5) << 3) + j;
      int e = l & 31;
      int n = d*DD + e;
      float v = 0.f;
      if (k < DD) v = W[n*DD + k];
      else if (k == DD) v = bv[n];
      dst[i] = f2bf(v);
    }
  } else if (bid < 450){                // Lw tail tiles (e 32..39, 4 d's packed)
    int t = bid - 360;
    int s = t / 10, tt = t - s*10;
    unsigned short* dst = ws + WS_LWT + (size_t)t*1536;
    const float* W = Lw + (size_t)s*64000;
    const float* bv = Lb + (size_t)s*1600;
    for (int i = tid; i < 1536; i += 256){
      int kf = i >> 9, q = i & 511, l = q >> 3, j = q & 7;
      int k = kf*16 + ((l >> 5) << 3) + j;
      int c = l & 31;
      int d = 4*tt + (c >> 3);
      int e = 32 + (c & 7);
      int n = d*DD + e;
      float v = 0.f;
      if (k < DD) v = W[n*DD + k];
      else if (k == DD) v = bv[n];
      dst[i] = f2bf(v);
    }
  } else if (bid < 459){                // Qw (+Eb+Qb at k=40, Ew at k=41)
    int s = bid - 450;
    unsigned short* dst = ws + WS_QW + (size_t)s*3072;
    const float* W = Qw + (size_t)s*1600;
    for (int i = tid; i < 3072; i += 256){
      int et = i / 1536, r = i - et*1536;
      int kf = r >> 9, q = r & 511, l = q >> 3, j = q & 7;
      int k = kf*16 + ((l >> 5) << 3) + j;
      int jc = et*32 + (l & 31);
      float v = 0.f;
      if (jc < DD){
        if (k < DD) v = W[jc*DD + k];
        else if (k == DD) v = Eb[s*DD + jc] + Qb[s*DD + jc];
        else if (k == DD+1) v = Ew[s*DD + jc];
      }
      dst[i] = f2bf(v);
    }
  } else if (bid < 468){                // Mw (+Mb at k=40)
    int s = bid - 459;
    unsigned short* dst = ws + WS_MW + (size_t)s*3072;
    const float* W = Mw + (size_t)s*1600;
    for (int i = tid; i < 3072; i += 256){
      int et = i / 1536, r = i - et*1536;
      int kf = r >> 9, q = r & 511, l = q >> 3, j = q & 7;
      int k = kf*16 + ((l >> 5) << 3) + j;
      int e = et*32 + (l & 31);
      float v = 0.f;
      if (e < DD){
        if (k < DD) v = W[e*DD + k];
        else if (k == DD) v = Mb[s*DD + e];
      }
      dst[i] = f2bf(v);
    }
  } else {                              // Tw (+Tb at k=40)
    int t = bid - 468;
    unsigned short* dst = ws + WS_TW + (size_t)t*1536;
    for (int i = tid; i < 1536; i += 256){
      int kf = i >> 9, q = i & 511, l = q >> 3, j = q & 7;
      int k = kf*16 + ((l >> 5) << 3) + j;
      int a = t*32 + (l & 31);
      float v = 0.f;
      if (a < ANUM){
        if (k < DD) v = Tw[(size_t)a*DD + k];
        else if (k == DD) v = Tb[a];
      }
      dst[i] = f2bf(v);
    }
  }
}

// r14 base, re-split for 768 thr / 12 waves (3 waves/SIMD; r13 showed more
// BLOCKS multiplies L2 fragment traffic, more WAVES per block does not).
// B: waves 0-9 own 4 full tiles (d=i*10+w) + 1 packed tail (t=w, triplet
//    prefetched at i==3). A(s+1): waves 10,11. C(s): waves 0,1.
// red transposed to [m*40+e][12] (dp=wave; slots 10,11 stay zero) so C's
// init is 3x f32x4 per reg instead of 10 scalar reads.
__global__ __launch_bounds__(768)
void star_main(const int* __restrict__ X,
               const int* __restrict__ T1,
               const int* __restrict__ T2,
               const float* __restrict__ emb,
               const unsigned short* __restrict__ ws,
               float* __restrict__ out)
{
  __shared__ __align__(16) unsigned short pbuf[2][3072]; // p-state, A-frag order
  __shared__ __align__(16) unsigned short aebf[2][3072]; // emb gather (dbuf); [1] = final h
  __shared__ __align__(16) float hT[2][DD*36];           // h-state, [d][m]
  __shared__ __align__(16) float red[MB*DD*12];          // tt partials [m*40+e][12]
  __shared__ int   aeidx[SLM1][MB];
  __shared__ float tvtab[SLM1][MB];

  const int tid = threadIdx.x;
  const int w = __builtin_amdgcn_readfirstlane(tid >> 6);   // 0..11
  const int l = tid & 63;
  const int col = l & 31, half = l >> 5;
  const int row0 = blockIdx.x * MB;

  // ---- prologue ----
  {
    unsigned int* p = (unsigned int*)&pbuf[0][0];
    for (int i = tid; i < 3072; i += 768) p[i] = 0u;
    unsigned int* a = (unsigned int*)&aebf[0][0];
    for (int i = tid; i < 3072; i += 768) a[i] = 0u;
    for (int i = tid; i < MB*DD*12; i += 768) red[i] = 0.f;  // C(0) sums zeros; dp 10,11 stay 0
  }
  if (tid < MB*SLM1){
    int m = tid / SLM1, s = tid - m*SLM1;
    int r = row0 + m;
    aeidx[s][m] = X[(size_t)r*40 + s*4 + 3];
    tvtab[s][m] = (float)(T1[r*SLM1 + s]*8 + T2[r*SLM1 + s]);
  }
  __syncthreads();
  if (tid < MB){
    int off = 2*1024 + (tid + 32)*8;    // k=40 (bias mult), k=41 (tvec)
    pbuf[0][off] = 0x3F80; pbuf[1][off] = 0x3F80;
    aebf[0][off] = 0x3F80; aebf[1][off] = 0x3F80;
    pbuf[0][off+1] = f2bf(tvtab[0][tid]);
    pbuf[1][off+1] = f2bf(tvtab[1][tid]);
  }
  if (tid < 320){  // gather ae(0)
    int m = tid / 10, q4 = tid - m*10;
    float4 v4 = *(const float4*)(emb + (size_t)aeidx[0][m]*DD + q4*4);
    #pragma unroll
    for (int c2 = 0; c2 < 4; ++c2){
      int k = q4*4 + c2, kf = k >> 4, kk = k & 15;
      aebf[0][kf*1024 + (m + ((kk >> 3) << 5))*8 + (kk & 7)] = f2bf(((const float*)&v4)[c2]);
    }
  }
  __syncthreads();
  // A(0): p1(0) = relu6(0@Qw + t*Ew + Eb + Qb), waves 0,1
  if (w < 2){
    short8 a0 = ((const short8*)&pbuf[0][0])[l];
    short8 a1 = ((const short8*)&pbuf[0][1024])[l];
    short8 a2 = ((const short8*)&pbuf[0][2048])[l];
    const unsigned short* qwb = ws + WS_QW + w*1536;
    f32x16 c = mfma3(a0, a1, a2, ((const short8*)qwb)[l],
                     ((const short8*)(qwb+512))[l], ((const short8*)(qwb+1024))[l]);
    int j = w*32 + col;
    if (j < DD){
      int kf = j >> 4, kk = j & 15;
      #pragma unroll
      for (int r = 0; r < 16; ++r){
        int m = (r & 3) + ((r >> 2) << 3) + (half << 2);
        pbuf[1][kf*1024 + (m + ((kk >> 3) << 5))*8 + (kk & 7)] = f2bf(relu6f(c[r]));
      }
    }
  }
  __syncthreads();

  // cross-step prefetch regs: next step's first full-tile triplet (d = w)
  short8 q00, q01, q02;

  for (int s = 0; s < SLM1; ++s){
    const int pcur = (s + 1) & 1;   // buffer holding p1(s)
    const int hrd  = s & 1;

    // ---- phase 1: B(s) (waves 0-9) + A(s+1) (waves 10,11) ----
    float4 gv; int gm = 0, gq = 0;
    const bool dog = (s < 8) && (tid < 320);
    if (dog){
      gm = tid / 10; gq = tid - gm*10;
      gv = *(const float4*)(emb + (size_t)aeidx[s+1][gm]*DD + gq*4);
    }
    short8 pa0 = ((const short8*)&pbuf[pcur][0])[l];
    short8 pa1 = ((const short8*)&pbuf[pcur][1024])[l];
    short8 pa2 = ((const short8*)&pbuf[pcur][2048])[l];

    if (s > 0 && w < 10){
      const float* hbase = &hT[hrd][half << 2];
      const unsigned short* lwf = ws + WS_LWF + (size_t)(s*40)*1536;

      // 4 full tiles (d = i*10+w); i==3 prefetches the TAIL triplet (t=w)
      f32x16 tt = {0,0,0,0,0,0,0,0,0,0,0,0,0,0,0,0};
      short8 b0 = q00, b1 = q01, b2 = q02;   // prefetched last step
      #pragma unroll
      for (int i = 0; i < 4; ++i){
        const unsigned short* nf = (i < 3)
            ? lwf + (size_t)((i+1)*10 + w)*1536
            : ws + WS_LWT + (size_t)(s*10 + w)*1536;
        short8 n0 = ((const short8*)nf)[l];
        short8 n1 = ((const short8*)(nf + 512))[l];
        short8 n2 = ((const short8*)(nf + 1024))[l];
        const float* hb = hbase + (i*10 + w)*36;
        f32x4 h0 = *(const f32x4*)(hb);
        f32x4 h1 = *(const f32x4*)(hb + 8);
        f32x4 h2 = *(const f32x4*)(hb + 16);
        f32x4 h3 = *(const f32x4*)(hb + 24);
        f32x16 c = mfma3(pa0, pa1, pa2, b0, b1, b2);
        #pragma unroll
        for (int q = 0; q < 4; ++q){
          tt[q]    = fmaf(h0[q], relu6f(c[q]),    tt[q]);
          tt[4+q]  = fmaf(h1[q], relu6f(c[4+q]),  tt[4+q]);
          tt[8+q]  = fmaf(h2[q], relu6f(c[8+q]),  tt[8+q]);
          tt[12+q] = fmaf(h3[q], relu6f(c[12+q]), tt[12+q]);
        }
        b0 = n0; b1 = n1; b2 = n2;
      }
      // commit full-tile partials: red[(m*40+col)*12 + w]
      #pragma unroll
      for (int r = 0; r < 16; ++r){
        int m = (r & 3) + ((r >> 2) << 3) + (half << 2);
        red[(m*DD + col)*12 + w] = tt[r];
      }

      // cross-step prefetch for s+1 (in flight through tail + C + barrier)
      if (s < 8){
        const unsigned short* n0p = ws + WS_LWF + (size_t)((s+1)*40 + w)*1536;
        q00 = ((const short8*)n0p)[l];
        q01 = ((const short8*)(n0p + 512))[l];
        q02 = ((const short8*)(n0p + 1024))[l];
      }

      // tail tile t=w: covers d=4w+(col>>3), e=32+(col&7); triplet in b0..b2
      {
        f32x16 c = mfma3(pa0, pa1, pa2, b0, b1, b2);
        int dt = 4*w + (col >> 3);
        const float* hb = &hT[hrd][dt*36 + (half << 2)];
        f32x16 tacc;
        #pragma unroll
        for (int g = 0; g < 4; ++g){
          f32x4 hg = *(const f32x4*)(hb + g*8);
          #pragma unroll
          for (int q = 0; q < 4; ++q){
            float val = hg[q]*relu6f(c[g*4+q]);
            val += __shfl_xor(val, 8);
            val += __shfl_xor(val, 16);
            tacc[g*4+q] = val;
          }
        }
        if (col < 8){
          #pragma unroll
          for (int r = 0; r < 16; ++r){
            int m = (r & 3) + ((r >> 2) << 3) + (half << 2);
            red[(m*DD + 32 + col)*12 + w] = tacc[r];
          }
        }
      }
    } else if (s == 0 && w < 10 && s < 8){
      // prefetch for step 1 (B(0) is skipped)
      const unsigned short* n0p = ws + WS_LWF + (size_t)((s+1)*40 + w)*1536;
      q00 = ((const short8*)n0p)[l];
      q01 = ((const short8*)(n0p + 512))[l];
      q02 = ((const short8*)(n0p + 1024))[l];
    } else if (w >= 10 && s < 8){
      // A(s+1) on waves 10,11 (reads p1(s)+tvec(s+1); writes pbuf[s&1]).
      // tvec(s+2) write below touches kf=2 rows 32+; A writes rows <32 - disjoint.
      const int et = w - 10;
      const unsigned short* qwb = ws + WS_QW + (size_t)(s+1)*3072 + (size_t)et*1536;
      f32x16 c = mfma3(pa0, pa1, pa2, ((const short8*)qwb)[l],
                       ((const short8*)(qwb+512))[l], ((const short8*)(qwb+1024))[l]);
      int j = et*32 + col;
      if (j < DD){
        int kf = j >> 4, kk = j & 15;
        #pragma unroll
        for (int r = 0; r < 16; ++r){
          int m = (r & 3) + ((r >> 2) << 3) + (half << 2);
          pbuf[s & 1][kf*1024 + (m + ((kk >> 3) << 5))*8 + (kk & 7)] = f2bf(relu6f(c[r]));
        }
      }
    }
    // late writes: ae(s+1); tvec(s+2) into pbuf[s&1] k=41 slot
    if (dog){
      unsigned short* dst = &aebf[(s+1) & 1][0];
      #pragma unroll
      for (int c2 = 0; c2 < 4; ++c2){
        int k = gq*4 + c2, kf = k >> 4, kk = k & 15;
        dst[kf*1024 + (gm + ((kk >> 3) << 5))*8 + (kk & 7)] = f2bf(((const float*)&gv)[c2]);
      }
    }
    if (s <= 6 && tid < MB)
      pbuf[s & 1][2*1024 + (tid + 32)*8 + 1] = f2bf(tvtab[s+2][tid]);
    __syncthreads();

    // ---- phase 2: C(s) only (waves 0,1) ----
    if (w < 2){
      short8 a0 = ((const short8*)&aebf[s & 1][0])[l];
      short8 a1 = ((const short8*)&aebf[s & 1][1024])[l];
      short8 a2 = ((const short8*)&aebf[s & 1][2048])[l];
      const unsigned short* mwb = ws + WS_MW + (size_t)s*3072 + w*1536;
      int e = w*32 + col;
      f32x16 c = {0,0,0,0,0,0,0,0,0,0,0,0,0,0,0,0};
      if (e < DD){
        #pragma unroll
        for (int r = 0; r < 16; ++r){
          int m = (r & 3) + ((r >> 2) << 3) + (half << 2);
          const f32x4* rp = (const f32x4*)&red[(m*DD + e)*12];
          f32x4 v0 = rp[0], v1 = rp[1], v2 = rp[2];   // dp 10,11 are zero
          c[r] = ((v0[0]+v0[1])+(v0[2]+v0[3]))
               + ((v1[0]+v1[1])+(v1[2]+v1[3]))
               + ((v2[0]+v2[1])+(v2[2]+v2[3]));
        }
      }
      c = __builtin_amdgcn_mfma_f32_32x32x16_bf16(a0, ((const short8*)mwb)[l], c, 0, 0, 0);
      c = __builtin_amdgcn_mfma_f32_32x32x16_bf16(a1, ((const short8*)(mwb+512))[l], c, 0, 0, 0);
      c = __builtin_amdgcn_mfma_f32_32x32x16_bf16(a2, ((const short8*)(mwb+1024))[l], c, 0, 0, 0);
      if (e < DD){
        int kf = e >> 4, kk = e & 15;
        #pragma unroll
        for (int r = 0; r < 16; ++r){
          int m = (r & 3) + ((r >> 2) << 3) + (half << 2);
          float v = relu6f(c[r]);
          hT[(s+1) & 1][e*36 + m] = v;
          if (s == SLM1-1)
            aebf[1][kf*1024 + (m + ((kk >> 3) << 5))*8 + (kk & 7)] = f2bf(v);
        }
      }
    }
    __syncthreads();
  }

  // ---- epilogue: out = h@Tw^T + Tb via MFMA (h-frag in aebf[1]) ----
  if (w < 9){
    const int t = w;
    short8 a0 = ((const short8*)&aebf[1][0])[l];
    short8 a1 = ((const short8*)&aebf[1][1024])[l];
    short8 a2 = ((const short8*)&aebf[1][2048])[l];
    const unsigned short* twb = ws + WS_TW + (size_t)t*1536;
    f32x16 c = mfma3(a0, a1, a2, ((const short8*)twb)[l],
                     ((const short8*)(twb+512))[l], ((const short8*)(twb+1024))[l]);
    int a = t*32 + col;
    if (a < ANUM){
      #pragma unroll
      for (int r = 0; r < 16; ++r){
        int m = (r & 3) + ((r >> 2) << 3) + (half << 2);
        out[(size_t)(row0 + m)*ANUM + a] = c[r];
      }
    }
  }
}

extern "C" void kernel_launch(void* const* d_in, const int* in_sizes, int n_in,
                              void* d_out, int out_size, void* d_ws, size_t ws_size,
                              hipStream_t stream) {
  const int*   X  = (const int*)  d_in[0];
  const int*   T1 = (const int*)  d_in[1];
  const int*   T2 = (const int*)  d_in[2];
  const float* Ew = (const float*)d_in[3];
  const float* Eb = (const float*)d_in[4];
  const float* Qw = (const float*)d_in[5];
  const float* Qb = (const float*)d_in[6];
  const float* Lw = (const float*)d_in[7];
  const float* Lb = (const float*)d_in[8];
  const float* Mw = (const float*)d_in[9];
  const float* Mb = (const float*)d_in[10];
  const float* Tw = (const float*)d_in[11];
  const float* Tb = (const float*)d_in[12];
  const float* em = (const float*)d_in[13];
  unsigned short* ws = (unsigned short*)d_ws;
  float* out = (float*)d_out;

  prep_frags<<<dim3(477), dim3(256), 0, stream>>>(Qw, Lw, Mw, Tw, Ew, Eb, Qb,
                                                  Lb, Mb, Tb, ws);
  star_main<<<dim3(8192 / MB), dim3(768), 0, stream>>>(X, T1, T2, em, ws, out);
}

// Round 16
// 64.860 us; speedup vs baseline: 1.0764x; 1.0764x over previous
//
#include <hip/hip_runtime.h>

#define DD 40
#define SLM1 9
#define ANUM 268
#define MB 32
#define RSTR 10   // red inner stride (f32): slices 0..7 = waves, 8..9 pad.
                  // stride-10 -> write banks 2-way aliased only (free, m136);
                  // C reads 2x f32x4 per reg instead of 8 scalars.

typedef __attribute__((ext_vector_type(8))) short short8;
typedef __attribute__((ext_vector_type(4))) float f32x4;
typedef __attribute__((ext_vector_type(16))) float f32x16;

// ws offsets (u16 units) -- identical layout to r12/r14
#define WS_LWF ((size_t)0)        // full tiles: (s*40+d)*1536 ; e=0..31
#define WS_LWT ((size_t)552960)   // tail tiles: (s*10+t)*1536 ; col c -> d=4t+(c>>3), e=32+(c&7)
#define WS_QW  ((size_t)691200)   // s*3072 (+ et*1536)
#define WS_MW  ((size_t)718848)   // s*3072
#define WS_TW  ((size_t)746496)   // t*1536

__device__ __forceinline__ unsigned short f2bf(float f){
  unsigned int u = __float_as_uint(f);
  u += 0x7FFFu + ((u >> 16) & 1u);
  return (unsigned short)(u >> 16);
}
__device__ __forceinline__ float relu6f(float v){
  return fminf(fmaxf(v, 0.0f), 6.0f);
}

__device__ __forceinline__ f32x16 mfma3(short8 a0, short8 a1, short8 a2,
                                        short8 b0, short8 b1, short8 b2){
  f32x16 c = {0,0,0,0,0,0,0,0,0,0,0,0,0,0,0,0};
  c = __builtin_amdgcn_mfma_f32_32x32x16_bf16(a0, b0, c, 0, 0, 0);
  c = __builtin_amdgcn_mfma_f32_32x32x16_bf16(a1, b1, c, 0, 0, 0);
  c = __builtin_amdgcn_mfma_f32_32x32x16_bf16(a2, b2, c, 0, 0, 0);
  return c;
}

// Build 32x32x16 MFMA B-fragments with bias rows folded into K-pad slots.
// B layout: col = l&31, k = 8*(l>>5)+j (+16*kf).  (verified r3-r15)
// 512 threads (r16: halves iteration count; prep was ~6us of the total)
__global__ __launch_bounds__(512)
void prep_frags(const float* __restrict__ Qw, const float* __restrict__ Lw,
                const float* __restrict__ Mw, const float* __restrict__ Tw,
                const float* __restrict__ Ew, const float* __restrict__ Eb,
                const float* __restrict__ Qb, const float* __restrict__ Lb,
                const float* __restrict__ Mb, const float* __restrict__ Tb,
                unsigned short* __restrict__ ws)
{
  const int bid = blockIdx.x, tid = threadIdx.x;
  if (bid < 360){                       // Lw full tiles (e 0..31), one per (s,d)
    int s = bid / 40, d = bid - s*40;
    unsigned short* dst = ws + WS_LWF + (size_t)bid*1536;
    const float* W = Lw + (size_t)s*64000;
    const float* bv = Lb + (size_t)s*1600;
    for (int i = tid; i < 1536; i += 512){
      int kf = i >> 9, q = i & 511, l = q >> 3, j = q & 7;
      int k = kf*16 + ((l >> 5) << 3) + j;
      int e = l & 31;
      int n = d*DD + e;
      float v = 0.f;
      if (k < DD) v = W[n*DD + k];
      else if (k == DD) v = bv[n];
      dst[i] = f2bf(v);
    }
  } else if (bid < 450){                // Lw tail tiles (e 32..39, 4 d's packed)
    int t = bid - 360;
    int s = t / 10, tt = t - s*10;
    unsigned short* dst = ws + WS_LWT + (size_t)t*1536;
    const float* W = Lw + (size_t)s*64000;
    const float* bv = Lb + (size_t)s*1600;
    for (int i = tid; i < 1536; i += 512){
      int kf = i >> 9, q = i & 511, l = q >> 3, j = q & 7;
      int k = kf*16 + ((l >> 5) << 3) + j;
      int c = l & 31;
      int d = 4*tt + (c >> 3);
      int e = 32 + (c & 7);
      int n = d*DD + e;
      float v = 0.f;
      if (k < DD) v = W[n*DD + k];
      else if (k == DD) v = bv[n];
      dst[i] = f2bf(v);
    }
  } else if (bid < 459){                // Qw (+Eb+Qb at k=40, Ew at k=41)
    int s = bid - 450;
    unsigned short* dst = ws + WS_QW + (size_t)s*3072;
    const float* W = Qw + (size_t)s*1600;
    for (int i = tid; i < 3072; i += 512){
      int et = i / 1536, r = i - et*1536;
      int kf = r >> 9, q = r & 511, l = q >> 3, j = q & 7;
      int k = kf*16 + ((l >> 5) << 3) + j;
      int jc = et*32 + (l & 31);
      float v = 0.f;
      if (jc < DD){
        if (k < DD) v = W[jc*DD + k];
        else if (k == DD) v = Eb[s*DD + jc] + Qb[s*DD + jc];
        else if (k == DD+1) v = Ew[s*DD + jc];
      }
      dst[i] = f2bf(v);
    }
  } else if (bid < 468){                // Mw (+Mb at k=40)
    int s = bid - 459;
    unsigned short* dst = ws + WS_MW + (size_t)s*3072;
    const float* W = Mw + (size_t)s*1600;
    for (int i = tid; i < 3072; i += 512){
      int et = i / 1536, r = i - et*1536;
      int kf = r >> 9, q = r & 511, l = q >> 3, j = q & 7;
      int k = kf*16 + ((l >> 5) << 3) + j;
      int e = et*32 + (l & 31);
      float v = 0.f;
      if (e < DD){
        if (k < DD) v = W[e*DD + k];
        else if (k == DD) v = Mb[s*DD + e];
      }
      dst[i] = f2bf(v);
    }
  } else {                              // Tw (+Tb at k=40)
    int t = bid - 468;
    unsigned short* dst = ws + WS_TW + (size_t)t*1536;
    for (int i = tid; i < 1536; i += 512){
      int kf = i >> 9, q = i & 511, l = q >> 3, j = q & 7;
      int k = kf*16 + ((l >> 5) << 3) + j;
      int a = t*32 + (l & 31);
      float v = 0.f;
      if (a < ANUM){
        if (k < DD) v = Tw[(size_t)a*DD + k];
        else if (k == DD) v = Tb[a];
      }
      dst[i] = f2bf(v);
    }
  }
}

// r14 base (best, 57.3us; 512thr is the only shape with a 128-VGPR budget --
// allocator targets 512/(2blk*waves/4EU) regardless of LDS/attributes, r3-r15).
// r16 delta: red transposed to [m*40+e][10] so C's init is 2x f32x4 + 7 adds
// per reg instead of 8 scalar LDS reads (C chain was the longest remaining
// serialized segment; 6 of 8 waves idle during it).
__global__ __launch_bounds__(512)
void star_main(const int* __restrict__ X,
               const int* __restrict__ T1,
               const int* __restrict__ T2,
               const float* __restrict__ emb,
               const unsigned short* __restrict__ ws,
               float* __restrict__ out)
{
  __shared__ __align__(16) unsigned short pbuf[2][3072]; // p-state, A-frag order
  __shared__ __align__(16) unsigned short aebf[2][3072]; // emb gather (dbuf); [1] = final h
  __shared__ __align__(16) float hT[2][DD*36];           // h-state, [d][m]
  __shared__ __align__(16) float red[MB*DD*RSTR];        // tt partials [m*40+e][10]
  __shared__ int   aeidx[SLM1][MB];
  __shared__ float tvtab[SLM1][MB];

  const int tid = threadIdx.x;
  const int w = __builtin_amdgcn_readfirstlane(tid >> 6);
  const int l = tid & 63;
  const int col = l & 31, half = l >> 5;
  const int row0 = blockIdx.x * MB;

  // ---- prologue ----
  {
    unsigned int* p = (unsigned int*)&pbuf[0][0];
    for (int i = tid; i < 3072; i += 512) p[i] = 0u;
    unsigned int* a = (unsigned int*)&aebf[0][0];
    for (int i = tid; i < 3072; i += 512) a[i] = 0u;
    for (int i = tid; i < MB*DD*RSTR; i += 512) red[i] = 0.f;  // C(0) sums zeros
  }
  if (tid < MB*SLM1){
    int m = tid / SLM1, s = tid - m*SLM1;
    int r = row0 + m;
    aeidx[s][m] = X[(size_t)r*40 + s*4 + 3];
    tvtab[s][m] = (float)(T1[r*SLM1 + s]*8 + T2[r*SLM1 + s]);
  }
  __syncthreads();
  if (tid < MB){
    int off = 2*1024 + (tid + 32)*8;    // k=40 (bias mult), k=41 (tvec)
    pbuf[0][off] = 0x3F80; pbuf[1][off] = 0x3F80;
    aebf[0][off] = 0x3F80; aebf[1][off] = 0x3F80;
    pbuf[0][off+1] = f2bf(tvtab[0][tid]);
    pbuf[1][off+1] = f2bf(tvtab[1][tid]);
  }
  if (tid < 320){  // gather ae(0)
    int m = tid / 10, q4 = tid - m*10;
    float4 v4 = *(const float4*)(emb + (size_t)aeidx[0][m]*DD + q4*4);
    #pragma unroll
    for (int c2 = 0; c2 < 4; ++c2){
      int k = q4*4 + c2, kf = k >> 4, kk = k & 15;
      aebf[0][kf*1024 + (m + ((kk >> 3) << 5))*8 + (kk & 7)] = f2bf(((const float*)&v4)[c2]);
    }
  }
  __syncthreads();
  // A(0): p1(0) = relu6(0@Qw + t*Ew + Eb + Qb), waves 0,1
  if (w < 2){
    short8 a0 = ((const short8*)&pbuf[0][0])[l];
    short8 a1 = ((const short8*)&pbuf[0][1024])[l];
    short8 a2 = ((const short8*)&pbuf[0][2048])[l];
    const unsigned short* qwb = ws + WS_QW + w*1536;
    f32x16 c = mfma3(a0, a1, a2, ((const short8*)qwb)[l],
                     ((const short8*)(qwb+512))[l], ((const short8*)(qwb+1024))[l]);
    int j = w*32 + col;
    if (j < DD){
      int kf = j >> 4, kk = j & 15;
      #pragma unroll
      for (int r = 0; r < 16; ++r){
        int m = (r & 3) + ((r >> 2) << 3) + (half << 2);
        pbuf[1][kf*1024 + (m + ((kk >> 3) << 5))*8 + (kk & 7)] = f2bf(relu6f(c[r]));
      }
    }
  }
  __syncthreads();

  // cross-step prefetch regs: next step's first two full-tile triplets
  short8 q00, q01, q02, q10, q11, q12;

  for (int s = 0; s < SLM1; ++s){
    const int pcur = (s + 1) & 1;   // buffer holding p1(s)
    const int hrd  = s & 1;

    // ---- phase 1: B(s) (all waves) + A(s+1) (waves 6,7) ----
    float4 gv; int gm = 0, gq = 0;
    const bool dog = (s < 8) && (tid < 320);
    if (dog){
      gm = tid / 10; gq = tid - gm*10;
      gv = *(const float4*)(emb + (size_t)aeidx[s+1][gm]*DD + gq*4);
    }
    short8 pa0 = ((const short8*)&pbuf[pcur][0])[l];
    short8 pa1 = ((const short8*)&pbuf[pcur][1024])[l];
    short8 pa2 = ((const short8*)&pbuf[pcur][2048])[l];
    if (s > 0){
      const float* hbase = &hT[hrd][half << 2];

      // full tiles: d = i*8+w; first two triplets from cross-step prefetch
      f32x16 tt = {0,0,0,0,0,0,0,0,0,0,0,0,0,0,0,0};
      {
        const unsigned short* lwf = ws + WS_LWF + (size_t)(s*40)*1536;
        short8 b00 = q00, b01 = q01, b02 = q02;
        short8 b10 = q10, b11 = q11, b12 = q12;
        #pragma unroll
        for (int i = 0; i < 5; ++i){
          short8 nb0, nb1, nb2;
          if (i < 3){
            const unsigned short* nf = lwf + (size_t)((i+2)*8 + w)*1536;
            nb0 = ((const short8*)nf)[l];
            nb1 = ((const short8*)(nf + 512))[l];
            nb2 = ((const short8*)(nf + 1024))[l];
          }
          const float* hb = hbase + (i*8 + w)*36;
          f32x4 h0 = *(const f32x4*)(hb);
          f32x4 h1 = *(const f32x4*)(hb + 8);
          f32x4 h2 = *(const f32x4*)(hb + 16);
          f32x4 h3 = *(const f32x4*)(hb + 24);
          f32x16 c = mfma3(pa0, pa1, pa2, b00, b01, b02);
          #pragma unroll
          for (int q = 0; q < 4; ++q){
            tt[q]    = fmaf(h0[q], relu6f(c[q]),    tt[q]);
            tt[4+q]  = fmaf(h1[q], relu6f(c[4+q]),  tt[4+q]);
            tt[8+q]  = fmaf(h2[q], relu6f(c[8+q]),  tt[8+q]);
            tt[12+q] = fmaf(h3[q], relu6f(c[12+q]), tt[12+q]);
          }
          b00 = b10; b01 = b11; b02 = b12;
          if (i < 3){ b10 = nb0; b11 = nb1; b12 = nb2; }
        }
      }
      // commit full-tile partials: red[(m*40+col)*10 + w] (2-way bank alias only)
      #pragma unroll
      for (int r = 0; r < 16; ++r){
        int m = (r & 3) + ((r >> 2) << 3) + (half << 2);
        red[(m*DD + col)*RSTR + w] = tt[r];
      }
    }

    // cross-step prefetch for step s+1
    if (s < 8){
      const unsigned short* nl = ws + WS_LWF + (size_t)((s+1)*40)*1536;
      const unsigned short* n0 = nl + (size_t)w*1536;
      q00 = ((const short8*)n0)[l];
      q01 = ((const short8*)(n0 + 512))[l];
      q02 = ((const short8*)(n0 + 1024))[l];
      const unsigned short* n1 = nl + (size_t)(8 + w)*1536;
      q10 = ((const short8*)n1)[l];
      q11 = ((const short8*)(n1 + 512))[l];
      q12 = ((const short8*)(n1 + 1024))[l];
    }

    if (s > 0 && w < 6){
      // packed tail tiles on waves 0-5: tile t covers d=4t+(col>>3), e=32+(col&7)
      const unsigned short* lwt = ws + WS_LWT + (size_t)(s*10)*1536;
      f32x16 tacc = {0,0,0,0,0,0,0,0,0,0,0,0,0,0,0,0};
      for (int tti = w; tti < 10; tti += 6){
        const unsigned short* ft = lwt + (size_t)tti*1536;
        short8 t0 = ((const short8*)ft)[l];
        short8 t1 = ((const short8*)(ft + 512))[l];
        short8 t2 = ((const short8*)(ft + 1024))[l];
        f32x16 c = mfma3(pa0, pa1, pa2, t0, t1, t2);
        int dt = 4*tti + (col >> 3);
        const float* hb = &hT[hrd][dt*36 + (half << 2)];
        #pragma unroll
        for (int g = 0; g < 4; ++g){
          f32x4 hg = *(const f32x4*)(hb + g*8);
          #pragma unroll
          for (int q = 0; q < 4; ++q){
            float val = hg[q]*relu6f(c[g*4+q]);
            val += __shfl_xor(val, 8);
            val += __shfl_xor(val, 16);
            tacc[g*4+q] += val;
          }
        }
      }
      if (col < 8){
        #pragma unroll
        for (int r = 0; r < 16; ++r){
          int m = (r & 3) + ((r >> 2) << 3) + (half << 2);
          red[(m*DD + 32 + col)*RSTR + w] = tacc[r];
        }
      }
    } else if (w >= 6 && s < 8){
      // A(s+1) on waves 6,7 (reads p1(s) + tvec(s+1); writes pbuf[s&1])
      const int et = w - 6;
      const unsigned short* qwb = ws + WS_QW + (size_t)(s+1)*3072 + (size_t)et*1536;
      f32x16 c = mfma3(pa0, pa1, pa2, ((const short8*)qwb)[l],
                       ((const short8*)(qwb+512))[l], ((const short8*)(qwb+1024))[l]);
      int j = et*32 + col;
      if (j < DD){
        int kf = j >> 4, kk = j & 15;
        #pragma unroll
        for (int r = 0; r < 16; ++r){
          int m = (r & 3) + ((r >> 2) << 3) + (half << 2);
          pbuf[s & 1][kf*1024 + (m + ((kk >> 3) << 5))*8 + (kk & 7)] = f2bf(relu6f(c[r]));
        }
      }
    }
    // late writes: ae(s+1); tvec(s+2) into pbuf[s&1] k=41 (A(s+2) reads it;
    // B(s+1) multiplies k=41 against Lw's zero row -> no hazard; A(s+1) above
    // writes only rows m<32 of the kf=2 block, tvec uses rows 32+ -> disjoint)
    if (dog){
      unsigned short* dst = &aebf[(s+1) & 1][0];
      #pragma unroll
      for (int c2 = 0; c2 < 4; ++c2){
        int k = gq*4 + c2, kf = k >> 4, kk = k & 15;
        dst[kf*1024 + (gm + ((kk >> 3) << 5))*8 + (kk & 7)] = f2bf(((const float*)&gv)[c2]);
      }
    }
    if (s <= 6 && tid < MB)
      pbuf[s & 1][2*1024 + (tid + 32)*8 + 1] = f2bf(tvtab[s+2][tid]);
    __syncthreads();

    // ---- phase 2: C(s) only (waves 0,1) ----
    if (w < 2){
      short8 a0 = ((const short8*)&aebf[s & 1][0])[l];
      short8 a1 = ((const short8*)&aebf[s & 1][1024])[l];
      short8 a2 = ((const short8*)&aebf[s & 1][2048])[l];
      const unsigned short* mwb = ws + WS_MW + (size_t)s*3072 + w*1536;
      int e = w*32 + col;
      f32x16 c = {0,0,0,0,0,0,0,0,0,0,0,0,0,0,0,0};
      if (e < DD){
        #pragma unroll
        for (int r = 0; r < 16; ++r){
          int m = (r & 3) + ((r >> 2) << 3) + (half << 2);
          const float* rp = &red[(m*DD + e)*RSTR];
          f32x4 v0 = *(const f32x4*)(rp);
          f32x4 v1 = *(const f32x4*)(rp + 4);
          c[r] = ((v0[0]+v0[1])+(v0[2]+v0[3]))
               + ((v1[0]+v1[1])+(v1[2]+v1[3]));
        }
      }
      c = __builtin_amdgcn_mfma_f32_32x32x16_bf16(a0, ((const short8*)mwb)[l], c, 0, 0, 0);
      c = __builtin_amdgcn_mfma_f32_32x32x16_bf16(a1, ((const short8*)(mwb+512))[l], c, 0, 0, 0);
      c = __builtin_amdgcn_mfma_f32_32x32x16_bf16(a2, ((const short8*)(mwb+1024))[l], c, 0, 0, 0);
      if (e < DD){
        int kf = e >> 4, kk = e & 15;
        #pragma unroll
        for (int r = 0; r < 16; ++r){
          int m = (r & 3) + ((r >> 2) << 3) + (half << 2);
          float v = relu6f(c[r]);
          hT[(s+1) & 1][e*36 + m] = v;
          if (s == SLM1-1)
            aebf[1][kf*1024 + (m + ((kk >> 3) << 5))*8 + (kk & 7)] = f2bf(v);
        }
      }
    }
    __syncthreads();
  }

  // ---- epilogue: out = h@Tw^T + Tb via MFMA (h-frag in aebf[1]) ----
  for (int t = w; t < 9; t += 8){
    short8 a0 = ((const short8*)&aebf[1][0])[l];
    short8 a1 = ((const short8*)&aebf[1][1024])[l];
    short8 a2 = ((const short8*)&aebf[1][2048])[l];
    const unsigned short* twb = ws + WS_TW + (size_t)t*1536;
    f32x16 c = mfma3(a0, a1, a2, ((const short8*)twb)[l],
                     ((const short8*)(twb+512))[l], ((const short8*)(twb+1024))[l]);
    int a = t*32 + col;
    if (a < ANUM){
      #pragma unroll
      for (int r = 0; r < 16; ++r){
        int m = (r & 3) + ((r >> 2) << 3) + (half << 2);
        out[(size_t)(row0 + m)*ANUM + a] = c[r];
      }
    }
  }
}

extern "C" void kernel_launch(void* const* d_in, const int* in_sizes, int n_in,
                              void* d_out, int out_size, void* d_ws, size_t ws_size,
                              hipStream_t stream) {
  const int*   X  = (const int*)  d_in[0];
  const int*   T1 = (const int*)  d_in[1];
  const int*   T2 = (const int*)  d_in[2];
  const float* Ew = (const float*)d_in[3];
  const float* Eb = (const float*)d_in[4];
  const float* Qw = (const float*)d_in[5];
  const float* Qb = (const float*)d_in[6];
  const float* Lw = (const float*)d_in[7];
  const float* Lb = (const float*)d_in[8];
  const float* Mw = (const float*)d_in[9];
  const float* Mb = (const float*)d_in[10];
  const float* Tw = (const float*)d_in[11];
  const float* Tb = (const float*)d_in[12];
  const float* em = (const float*)d_in[13];
  unsigned short* ws = (unsigned short*)d_ws;
  float* out = (float*)d_out;

  prep_frags<<<dim3(477), dim3(512), 0, stream>>>(Qw, Lw, Mw, Tw, Ew, Eb, Qb,
                                                  Lb, Mb, Tb, ws);
  star_main<<<dim3(8192 / MB), dim3(512), 0, stream>>>(X, T1, T2, em, ws, out);
}

// Round 17
// 55.526 us; speedup vs baseline: 1.2573x; 1.1681x over previous
//
#include <hip/hip_runtime.h>

#define DD 40
#define SLM1 9
#define ANUM 268
#define MB 32

typedef __attribute__((ext_vector_type(8))) short short8;
typedef __attribute__((ext_vector_type(4))) float f32x4;
typedef __attribute__((ext_vector_type(16))) float f32x16;

// ws offsets (u16 units) -- identical layout to r12/r14
#define WS_LWF ((size_t)0)        // full tiles: (s*40+d)*1536 ; e=0..31
#define WS_LWT ((size_t)552960)   // tail tiles: (s*10+t)*1536 ; col c -> d=4t+(c>>3), e=32+(c&7)
#define WS_QW  ((size_t)691200)   // s*3072 (+ et*1536)
#define WS_MW  ((size_t)718848)   // s*3072
#define WS_TW  ((size_t)746496)   // t*1536

__device__ __forceinline__ unsigned short f2bf(float f){
  unsigned int u = __float_as_uint(f);
  u += 0x7FFFu + ((u >> 16) & 1u);
  return (unsigned short)(u >> 16);
}
__device__ __forceinline__ float relu6f(float v){
  return fminf(fmaxf(v, 0.0f), 6.0f);
}

__device__ __forceinline__ f32x16 mfma3(short8 a0, short8 a1, short8 a2,
                                        short8 b0, short8 b1, short8 b2){
  f32x16 c = {0,0,0,0,0,0,0,0,0,0,0,0,0,0,0,0};
  c = __builtin_amdgcn_mfma_f32_32x32x16_bf16(a0, b0, c, 0, 0, 0);
  c = __builtin_amdgcn_mfma_f32_32x32x16_bf16(a1, b1, c, 0, 0, 0);
  c = __builtin_amdgcn_mfma_f32_32x32x16_bf16(a2, b2, c, 0, 0, 0);
  return c;
}

// Build 32x32x16 MFMA B-fragments with bias rows folded into K-pad slots.
// B layout: col = l&31, k = 8*(l>>5)+j (+16*kf).  (verified r3-r16)
__global__ __launch_bounds__(512)
void prep_frags(const float* __restrict__ Qw, const float* __restrict__ Lw,
                const float* __restrict__ Mw, const float* __restrict__ Tw,
                const float* __restrict__ Ew, const float* __restrict__ Eb,
                const float* __restrict__ Qb, const float* __restrict__ Lb,
                const float* __restrict__ Mb, const float* __restrict__ Tb,
                unsigned short* __restrict__ ws)
{
  const int bid = blockIdx.x, tid = threadIdx.x;
  if (bid < 360){                       // Lw full tiles (e 0..31), one per (s,d)
    int s = bid / 40, d = bid - s*40;
    unsigned short* dst = ws + WS_LWF + (size_t)bid*1536;
    const float* W = Lw + (size_t)s*64000;
    const float* bv = Lb + (size_t)s*1600;
    for (int i = tid; i < 1536; i += 512){
      int kf = i >> 9, q = i & 511, l = q >> 3, j = q & 7;
      int k = kf*16 + ((l >> 5) << 3) + j;
      int e = l & 31;
      int n = d*DD + e;
      float v = 0.f;
      if (k < DD) v = W[n*DD + k];
      else if (k == DD) v = bv[n];
      dst[i] = f2bf(v);
    }
  } else if (bid < 450){                // Lw tail tiles (e 32..39, 4 d's packed)
    int t = bid - 360;
    int s = t / 10, tt = t - s*10;
    unsigned short* dst = ws + WS_LWT + (size_t)t*1536;
    const float* W = Lw + (size_t)s*64000;
    const float* bv = Lb + (size_t)s*1600;
    for (int i = tid; i < 1536; i += 512){
      int kf = i >> 9, q = i & 511, l = q >> 3, j = q & 7;
      int k = kf*16 + ((l >> 5) << 3) + j;
      int c = l & 31;
      int d = 4*tt + (c >> 3);
      int e = 32 + (c & 7);
      int n = d*DD + e;
      float v = 0.f;
      if (k < DD) v = W[n*DD + k];
      else if (k == DD) v = bv[n];
      dst[i] = f2bf(v);
    }
  } else if (bid < 459){                // Qw (+Eb+Qb at k=40, Ew at k=41)
    int s = bid - 450;
    unsigned short* dst = ws + WS_QW + (size_t)s*3072;
    const float* W = Qw + (size_t)s*1600;
    for (int i = tid; i < 3072; i += 512){
      int et = i / 1536, r = i - et*1536;
      int kf = r >> 9, q = r & 511, l = q >> 3, j = q & 7;
      int k = kf*16 + ((l >> 5) << 3) + j;
      int jc = et*32 + (l & 31);
      float v = 0.f;
      if (jc < DD){
        if (k < DD) v = W[jc*DD + k];
        else if (k == DD) v = Eb[s*DD + jc] + Qb[s*DD + jc];
        else if (k == DD+1) v = Ew[s*DD + jc];
      }
      dst[i] = f2bf(v);
    }
  } else if (bid < 468){                // Mw (+Mb at k=40)
    int s = bid - 459;
    unsigned short* dst = ws + WS_MW + (size_t)s*3072;
    const float* W = Mw + (size_t)s*1600;
    for (int i = tid; i < 3072; i += 512){
      int et = i / 1536, r = i - et*1536;
      int kf = r >> 9, q = r & 511, l = q >> 3, j = q & 7;
      int k = kf*16 + ((l >> 5) << 3) + j;
      int e = et*32 + (l & 31);
      float v = 0.f;
      if (e < DD){
        if (k < DD) v = W[e*DD + k];
        else if (k == DD) v = Mb[s*DD + e];
      }
      dst[i] = f2bf(v);
    }
  } else {                              // Tw (+Tb at k=40)
    int t = bid - 468;
    unsigned short* dst = ws + WS_TW + (size_t)t*1536;
    for (int i = tid; i < 1536; i += 512){
      int kf = i >> 9, q = i & 511, l = q >> 3, j = q & 7;
      int k = kf*16 + ((l >> 5) << 3) + j;
      int a = t*32 + (l & 31);
      float v = 0.f;
      if (a < ANUM){
        if (k < DD) v = Tw[(size_t)a*DD + k];
        else if (k == DD) v = Tb[a];
      }
      dst[i] = f2bf(v);
    }
  }
}

// r14 base (best; red back to [8][MB*DD] -- r16's [.][10] transpose doubled
// bank conflicts and regressed). r17 delta: dual-d MFMA streams in B --
// each wave runs its 5 full tiles as 2 interleaved-chain pairs + 1 single,
// so two independent MFMA dep-chains keep the matrix pipe fed (ILP; TLP is
// walled at 2 waves/SIMD per r13/r15). Stream regs double as carriers for
// the tail triplet (waves 0-5) / Qw triplet for A(s+1) (waves 6,7).
__global__ __launch_bounds__(512)
void star_main(const int* __restrict__ X,
               const int* __restrict__ T1,
               const int* __restrict__ T2,
               const float* __restrict__ emb,
               const unsigned short* __restrict__ ws,
               float* __restrict__ out)
{
  __shared__ __align__(16) unsigned short pbuf[2][3072]; // p-state, A-frag order
  __shared__ __align__(16) unsigned short aebf[2][3072]; // emb gather (dbuf); [1] = final h
  __shared__ __align__(16) float hT[2][DD*36];           // h-state, [d][m]
  __shared__ __align__(16) float red[8][MB*DD];          // tt partials per wave
  __shared__ int   aeidx[SLM1][MB];
  __shared__ float tvtab[SLM1][MB];

  const int tid = threadIdx.x;
  const int w = __builtin_amdgcn_readfirstlane(tid >> 6);
  const int l = tid & 63;
  const int col = l & 31, half = l >> 5;
  const int row0 = blockIdx.x * MB;

  // ---- prologue ----
  {
    unsigned int* p = (unsigned int*)&pbuf[0][0];
    for (int i = tid; i < 3072; i += 512) p[i] = 0u;
    unsigned int* a = (unsigned int*)&aebf[0][0];
    for (int i = tid; i < 3072; i += 512) a[i] = 0u;
    float* rr = &red[0][0];
    for (int i = tid; i < 8*MB*DD; i += 512) rr[i] = 0.f;  // C(0) sums zeros
  }
  if (tid < MB*SLM1){
    int m = tid / SLM1, s = tid - m*SLM1;
    int r = row0 + m;
    aeidx[s][m] = X[(size_t)r*40 + s*4 + 3];
    tvtab[s][m] = (float)(T1[r*SLM1 + s]*8 + T2[r*SLM1 + s]);
  }
  __syncthreads();
  if (tid < MB){
    int off = 2*1024 + (tid + 32)*8;    // k=40 (bias mult), k=41 (tvec)
    pbuf[0][off] = 0x3F80; pbuf[1][off] = 0x3F80;
    aebf[0][off] = 0x3F80; aebf[1][off] = 0x3F80;
    pbuf[0][off+1] = f2bf(tvtab[0][tid]);
    pbuf[1][off+1] = f2bf(tvtab[1][tid]);
  }
  if (tid < 320){  // gather ae(0)
    int m = tid / 10, q4 = tid - m*10;
    float4 v4 = *(const float4*)(emb + (size_t)aeidx[0][m]*DD + q4*4);
    #pragma unroll
    for (int c2 = 0; c2 < 4; ++c2){
      int k = q4*4 + c2, kf = k >> 4, kk = k & 15;
      aebf[0][kf*1024 + (m + ((kk >> 3) << 5))*8 + (kk & 7)] = f2bf(((const float*)&v4)[c2]);
    }
  }
  __syncthreads();
  // A(0): p1(0) = relu6(0@Qw + t*Ew + Eb + Qb), waves 0,1
  if (w < 2){
    short8 a0 = ((const short8*)&pbuf[0][0])[l];
    short8 a1 = ((const short8*)&pbuf[0][1024])[l];
    short8 a2 = ((const short8*)&pbuf[0][2048])[l];
    const unsigned short* qwb = ws + WS_QW + w*1536;
    f32x16 c = mfma3(a0, a1, a2, ((const short8*)qwb)[l],
                     ((const short8*)(qwb+512))[l], ((const short8*)(qwb+1024))[l]);
    int j = w*32 + col;
    if (j < DD){
      int kf = j >> 4, kk = j & 15;
      #pragma unroll
      for (int r = 0; r < 16; ++r){
        int m = (r & 3) + ((r >> 2) << 3) + (half << 2);
        pbuf[1][kf*1024 + (m + ((kk >> 3) << 5))*8 + (kk & 7)] = f2bf(relu6f(c[r]));
      }
    }
  }
  __syncthreads();

  // cross-step prefetch regs: next step's first pair (d = w, d = w+8)
  short8 q00, q01, q02, q10, q11, q12;

  for (int s = 0; s < SLM1; ++s){
    const int pcur = (s + 1) & 1;   // buffer holding p1(s)
    const int hrd  = s & 1;

    // ---- phase 1: B(s) (all waves, dual-stream) + A(s+1) (waves 6,7) ----
    float4 gv; int gm = 0, gq = 0;
    const bool dog = (s < 8) && (tid < 320);
    if (dog){
      gm = tid / 10; gq = tid - gm*10;
      gv = *(const float4*)(emb + (size_t)aeidx[s+1][gm]*DD + gq*4);
    }
    short8 pa0 = ((const short8*)&pbuf[pcur][0])[l];
    short8 pa1 = ((const short8*)&pbuf[pcur][1024])[l];
    short8 pa2 = ((const short8*)&pbuf[pcur][2048])[l];

    // stream regs; after the main loop B* carries the tail / Qw triplet
    short8 A0, A1, A2, B0, B1, B2;

    if (s > 0){
      const float* hbase = &hT[hrd][half << 2];
      const unsigned short* lwf = ws + WS_LWF + (size_t)(s*40)*1536;

      A0 = q00; A1 = q01; A2 = q02;    // d = w      (cross-step prefetch)
      B0 = q10; B1 = q11; B2 = q12;    // d = w+8
      f32x16 tt = {0,0,0,0,0,0,0,0,0,0,0,0,0,0,0,0};

      #pragma unroll
      for (int it = 0; it < 2; ++it){
        // prefetch next pair (it0: d=w+16,w+24 ; it1: d=w+32 + tail/Qw triplet)
        short8 NA0, NA1, NA2, NB0, NB1, NB2;
        if (it == 0){
          const unsigned short* fA = lwf + (size_t)(16 + w)*1536;
          NA0 = ((const short8*)fA)[l];
          NA1 = ((const short8*)(fA + 512))[l];
          NA2 = ((const short8*)(fA + 1024))[l];
          const unsigned short* fB = lwf + (size_t)(24 + w)*1536;
          NB0 = ((const short8*)fB)[l];
          NB1 = ((const short8*)(fB + 512))[l];
          NB2 = ((const short8*)(fB + 1024))[l];
        } else {
          const unsigned short* fA = lwf + (size_t)(32 + w)*1536;
          NA0 = ((const short8*)fA)[l];
          NA1 = ((const short8*)(fA + 512))[l];
          NA2 = ((const short8*)(fA + 1024))[l];
          const size_t qs = (s < 8) ? (size_t)(s + 1) : (size_t)8;
          const unsigned short* fB = (w < 6)
              ? ws + WS_LWT + (size_t)(s*10 + w)*1536
              : ws + WS_QW + qs*3072 + (size_t)(w - 6)*1536;
          NB0 = ((const short8*)fB)[l];
          NB1 = ((const short8*)(fB + 512))[l];
          NB2 = ((const short8*)(fB + 1024))[l];
        }
        // two independent MFMA chains, interleaved
        f32x16 ca = {0,0,0,0,0,0,0,0,0,0,0,0,0,0,0,0};
        f32x16 cb = {0,0,0,0,0,0,0,0,0,0,0,0,0,0,0,0};
        ca = __builtin_amdgcn_mfma_f32_32x32x16_bf16(pa0, A0, ca, 0, 0, 0);
        cb = __builtin_amdgcn_mfma_f32_32x32x16_bf16(pa0, B0, cb, 0, 0, 0);
        ca = __builtin_amdgcn_mfma_f32_32x32x16_bf16(pa1, A1, ca, 0, 0, 0);
        cb = __builtin_amdgcn_mfma_f32_32x32x16_bf16(pa1, B1, cb, 0, 0, 0);
        ca = __builtin_amdgcn_mfma_f32_32x32x16_bf16(pa2, A2, ca, 0, 0, 0);
        cb = __builtin_amdgcn_mfma_f32_32x32x16_bf16(pa2, B2, cb, 0, 0, 0);
        // contraction for both d's, one f32x4 of h per stream live
        const int dA = it*16 + w, dB = it*16 + 8 + w;
        const float* hA = hbase + dA*36;
        const float* hB = hbase + dB*36;
        #pragma unroll
        for (int g = 0; g < 4; ++g){
          f32x4 ha = *(const f32x4*)(hA + g*8);
          f32x4 hb = *(const f32x4*)(hB + g*8);
          #pragma unroll
          for (int q = 0; q < 4; ++q){
            tt[g*4+q] = fmaf(ha[q], relu6f(ca[g*4+q]), tt[g*4+q]);
            tt[g*4+q] = fmaf(hb[q], relu6f(cb[g*4+q]), tt[g*4+q]);
          }
        }
        A0 = NA0; A1 = NA1; A2 = NA2;
        B0 = NB0; B1 = NB1; B2 = NB2;
      }
      // single stream: d = w+32 (in A regs)
      {
        f32x16 c = mfma3(pa0, pa1, pa2, A0, A1, A2);
        const float* hb = hbase + (32 + w)*36;
        #pragma unroll
        for (int g = 0; g < 4; ++g){
          f32x4 hg = *(const f32x4*)(hb + g*8);
          #pragma unroll
          for (int q = 0; q < 4; ++q)
            tt[g*4+q] = fmaf(hg[q], relu6f(c[g*4+q]), tt[g*4+q]);
        }
      }
      // commit full-tile partials (plain stores, per-wave slice)
      #pragma unroll
      for (int r = 0; r < 16; ++r){
        int m = (r & 3) + ((r >> 2) << 3) + (half << 2);
        red[w][m*DD + col] = tt[r];
      }
    }

    // cross-step prefetch for step s+1 (first pair)
    if (s < 8){
      const unsigned short* nl = ws + WS_LWF + (size_t)((s+1)*40)*1536;
      const unsigned short* n0 = nl + (size_t)w*1536;
      q00 = ((const short8*)n0)[l];
      q01 = ((const short8*)(n0 + 512))[l];
      q02 = ((const short8*)(n0 + 1024))[l];
      const unsigned short* n1 = nl + (size_t)(8 + w)*1536;
      q10 = ((const short8*)n1)[l];
      q11 = ((const short8*)(n1 + 512))[l];
      q12 = ((const short8*)(n1 + 1024))[l];
    }

    if (s > 0 && w < 6){
      // packed tails, waves 0-5 stride 6 (w0:{0,6} w1:{1,7} w2:{2,8} w3:{3,9}
      // w4:{4} w5:{5}); first tile's triplet already in B regs (it1 prefetch)
      const unsigned short* lwt = ws + WS_LWT + (size_t)(s*10)*1536;
      const float* hb0;
      f32x16 tacc = {0,0,0,0,0,0,0,0,0,0,0,0,0,0,0,0};
      {
        f32x16 c = mfma3(pa0, pa1, pa2, B0, B1, B2);
        int dt = 4*w + (col >> 3);
        hb0 = &hT[hrd][dt*36 + (half << 2)];
        #pragma unroll
        for (int g = 0; g < 4; ++g){
          f32x4 hg = *(const f32x4*)(hb0 + g*8);
          #pragma unroll
          for (int q = 0; q < 4; ++q){
            float val = hg[q]*relu6f(c[g*4+q]);
            val += __shfl_xor(val, 8);
            val += __shfl_xor(val, 16);
            tacc[g*4+q] += val;
          }
        }
      }
      if (w < 4){
        const int t2 = w + 6;
        const unsigned short* ft = lwt + (size_t)t2*1536;
        short8 t0 = ((const short8*)ft)[l];
        short8 t1 = ((const short8*)(ft + 512))[l];
        short8 t2r = ((const short8*)(ft + 1024))[l];
        f32x16 c = mfma3(pa0, pa1, pa2, t0, t1, t2r);
        int dt = 4*t2 + (col >> 3);
        const float* hb = &hT[hrd][dt*36 + (half << 2)];
        #pragma unroll
        for (int g = 0; g < 4; ++g){
          f32x4 hg = *(const f32x4*)(hb + g*8);
          #pragma unroll
          for (int q = 0; q < 4; ++q){
            float val = hg[q]*relu6f(c[g*4+q]);
            val += __shfl_xor(val, 8);
            val += __shfl_xor(val, 16);
            tacc[g*4+q] += val;
          }
        }
      }
      if (col < 8){
        #pragma unroll
        for (int r = 0; r < 16; ++r){
          int m = (r & 3) + ((r >> 2) << 3) + (half << 2);
          red[w][m*DD + 32 + col] = tacc[r];
        }
      }
    } else if (w >= 6 && s < 8){
      // A(s+1) on waves 6,7: Qw triplet in B regs (s>0) or loaded inline (s==0)
      short8 Q0, Q1, Q2;
      if (s == 0){
        const unsigned short* qwb = ws + WS_QW + (size_t)(s+1)*3072 + (size_t)(w-6)*1536;
        Q0 = ((const short8*)qwb)[l];
        Q1 = ((const short8*)(qwb + 512))[l];
        Q2 = ((const short8*)(qwb + 1024))[l];
      } else {
        Q0 = B0; Q1 = B1; Q2 = B2;
      }
      f32x16 c = mfma3(pa0, pa1, pa2, Q0, Q1, Q2);
      int j = (w - 6)*32 + col;
      if (j < DD){
        int kf = j >> 4, kk = j & 15;
        #pragma unroll
        for (int r = 0; r < 16; ++r){
          int m = (r & 3) + ((r >> 2) << 3) + (half << 2);
          pbuf[s & 1][kf*1024 + (m + ((kk >> 3) << 5))*8 + (kk & 7)] = f2bf(relu6f(c[r]));
        }
      }
    }
    // late writes: ae(s+1); tvec(s+2) into pbuf[s&1] k=41 (A(s+2) reads it;
    // B(s+1) multiplies k=41 against Lw's zero row -> no hazard; A(s+1) above
    // writes only rows m<32 of the kf=2 block, tvec uses rows 32+ -> disjoint)
    if (dog){
      unsigned short* dst = &aebf[(s+1) & 1][0];
      #pragma unroll
      for (int c2 = 0; c2 < 4; ++c2){
        int k = gq*4 + c2, kf = k >> 4, kk = k & 15;
        dst[kf*1024 + (gm + ((kk >> 3) << 5))*8 + (kk & 7)] = f2bf(((const float*)&gv)[c2]);
      }
    }
    if (s <= 6 && tid < MB)
      pbuf[s & 1][2*1024 + (tid + 32)*8 + 1] = f2bf(tvtab[s+2][tid]);
    __syncthreads();

    // ---- phase 2: C(s) only (waves 0,1) ----
    if (w < 2){
      short8 a0 = ((const short8*)&aebf[s & 1][0])[l];
      short8 a1 = ((const short8*)&aebf[s & 1][1024])[l];
      short8 a2 = ((const short8*)&aebf[s & 1][2048])[l];
      const unsigned short* mwb = ws + WS_MW + (size_t)s*3072 + w*1536;
      int e = w*32 + col;
      f32x16 c = {0,0,0,0,0,0,0,0,0,0,0,0,0,0,0,0};
      if (e < DD){
        #pragma unroll
        for (int r = 0; r < 16; ++r){
          int m = (r & 3) + ((r >> 2) << 3) + (half << 2);
          float acc = red[0][m*DD + e];
          #pragma unroll
          for (int dp = 1; dp < 8; ++dp) acc += red[dp][m*DD + e];
          c[r] = acc;
        }
      }
      c = __builtin_amdgcn_mfma_f32_32x32x16_bf16(a0, ((const short8*)mwb)[l], c, 0, 0, 0);
      c = __builtin_amdgcn_mfma_f32_32x32x16_bf16(a1, ((const short8*)(mwb+512))[l], c, 0, 0, 0);
      c = __builtin_amdgcn_mfma_f32_32x32x16_bf16(a2, ((const short8*)(mwb+1024))[l], c, 0, 0, 0);
      if (e < DD){
        int kf = e >> 4, kk = e & 15;
        #pragma unroll
        for (int r = 0; r < 16; ++r){
          int m = (r & 3) + ((r >> 2) << 3) + (half << 2);
          float v = relu6f(c[r]);
          hT[(s+1) & 1][e*36 + m] = v;
          if (s == SLM1-1)
            aebf[1][kf*1024 + (m + ((kk >> 3) << 5))*8 + (kk & 7)] = f2bf(v);
        }
      }
    }
    __syncthreads();
  }

  // ---- epilogue: out = h@Tw^T + Tb via MFMA (h-frag in aebf[1]) ----
  for (int t = w; t < 9; t += 8){
    short8 a0 = ((const short8*)&aebf[1][0])[l];
    short8 a1 = ((const short8*)&aebf[1][1024])[l];
    short8 a2 = ((const short8*)&aebf[1][2048])[l];
    const unsigned short* twb = ws + WS_TW + (size_t)t*1536;
    f32x16 c = mfma3(a0, a1, a2, ((const short8*)twb)[l],
                     ((const short8*)(twb+512))[l], ((const short8*)(twb+1024))[l]);
    int a = t*32 + col;
    if (a < ANUM){
      #pragma unroll
      for (int r = 0; r < 16; ++r){
        int m = (r & 3) + ((r >> 2) << 3) + (half << 2);
        out[(size_t)(row0 + m)*ANUM + a] = c[r];
      }
    }
  }
}

extern "C" void kernel_launch(void* const* d_in, const int* in_sizes, int n_in,
                              void* d_out, int out_size, void* d_ws, size_t ws_size,
                              hipStream_t stream) {
  const int*   X  = (const int*)  d_in[0];
  const int*   T1 = (const int*)  d_in[1];
  const int*   T2 = (const int*)  d_in[2];
  const float* Ew = (const float*)d_in[3];
  const float* Eb = (const float*)d_in[4];
  const float* Qw = (const float*)d_in[5];
  const float* Qb = (const float*)d_in[6];
  const float* Lw = (const float*)d_in[7];
  const float* Lb = (const float*)d_in[8];
  const float* Mw = (const float*)d_in[9];
  const float* Mb = (const float*)d_in[10];
  const float* Tw = (const float*)d_in[11];
  const float* Tb = (const float*)d_in[12];
  const float* em = (const float*)d_in[13];
  unsigned short* ws = (unsigned short*)d_ws;
  float* out = (float*)d_out;

  prep_frags<<<dim3(477), dim3(512), 0, stream>>>(Qw, Lw, Mw, Tw, Ew, Eb, Qb,
                                                  Lb, Mb, Tb, ws);
  star_main<<<dim3(8192 / MB), dim3(512), 0, stream>>>(X, T1, T2, em, ws, out);
}

// Round 18
// 48.542 us; speedup vs baseline: 1.4382x; 1.1439x over previous
//
#include <hip/hip_runtime.h>

#define DD 40
#define SLM1 9
#define ANUM 268
#define MB 32
#define RST2 42   // red row stride (f32): 4*42 % 32 == 8 -> every read/write
                  // group lands <=2-way on banks (free, m136). r16's stride
                  // mistake re-audited for BOTH writers and readers.

typedef __attribute__((ext_vector_type(8))) short short8;
typedef __attribute__((ext_vector_type(4))) float f32x4;
typedef __attribute__((ext_vector_type(16))) float f32x16;

// ws offsets (u16 units)
#define WS_LWF ((size_t)0)        // full tiles: (s*40+d)*1536 ; e=0..31 (32x32 B-frag)
#define WS_LWT ((size_t)552960)   // tail tiles: (s*10+t)*1536 ; col c -> d=4t+(c>>3), e=32+(c&7)
#define WS_QW  ((size_t)691200)   // s*3072 (+ et*1536)   (32x32 B-frag)
#define WS_MW  ((size_t)718848)   // s*3072 + et*1024 + kf*512  (16x16 B-frag, r18)
#define WS_TW  ((size_t)746496)   // t*1536               (32x32 B-frag)

__device__ __forceinline__ unsigned short f2bf(float f){
  unsigned int u = __float_as_uint(f);
  u += 0x7FFFu + ((u >> 16) & 1u);
  return (unsigned short)(u >> 16);
}
__device__ __forceinline__ float relu6f(float v){
  return fminf(fmaxf(v, 0.0f), 6.0f);
}

__device__ __forceinline__ f32x16 mfma3(short8 a0, short8 a1, short8 a2,
                                        short8 b0, short8 b1, short8 b2){
  f32x16 c = {0,0,0,0,0,0,0,0,0,0,0,0,0,0,0,0};
  c = __builtin_amdgcn_mfma_f32_32x32x16_bf16(a0, b0, c, 0, 0, 0);
  c = __builtin_amdgcn_mfma_f32_32x32x16_bf16(a1, b1, c, 0, 0, 0);
  c = __builtin_amdgcn_mfma_f32_32x32x16_bf16(a2, b2, c, 0, 0, 0);
  return c;
}

// ae 16x16 A-frag offset for element (m,k): lane = ((k&31)>>3)*16 + (m&15)
__device__ __forceinline__ int ae16_off(int m, int k){
  return (m >> 4)*1024 + (k >> 5)*512 + (((k & 31) >> 3) << 7) + (m & 15)*8 + (k & 7);
}

// 32x32 B-frag: col = l&31, k = 8*(l>>5)+j (+16*kf)   (verified r3-r17)
// 16x16 B-frag: col = l&15, k = 8*(l>>4)+j (+32*kf)   (verified r2/r13)
__global__ __launch_bounds__(512)
void prep_frags(const float* __restrict__ Qw, const float* __restrict__ Lw,
                const float* __restrict__ Mw, const float* __restrict__ Tw,
                const float* __restrict__ Ew, const float* __restrict__ Eb,
                const float* __restrict__ Qb, const float* __restrict__ Lb,
                const float* __restrict__ Mb, const float* __restrict__ Tb,
                unsigned short* __restrict__ ws)
{
  const int bid = blockIdx.x, tid = threadIdx.x;
  if (bid < 360){                       // Lw full tiles (e 0..31), one per (s,d)
    int s = bid / 40, d = bid - s*40;
    unsigned short* dst = ws + WS_LWF + (size_t)bid*1536;
    const float* W = Lw + (size_t)s*64000;
    const float* bv = Lb + (size_t)s*1600;
    for (int i = tid; i < 1536; i += 512){
      int kf = i >> 9, q = i & 511, l = q >> 3, j = q & 7;
      int k = kf*16 + ((l >> 5) << 3) + j;
      int e = l & 31;
      int n = d*DD + e;
      float v = 0.f;
      if (k < DD) v = W[n*DD + k];
      else if (k == DD) v = bv[n];
      dst[i] = f2bf(v);
    }
  } else if (bid < 450){                // Lw tail tiles (e 32..39, 4 d's packed)
    int t = bid - 360;
    int s = t / 10, tt = t - s*10;
    unsigned short* dst = ws + WS_LWT + (size_t)t*1536;
    const float* W = Lw + (size_t)s*64000;
    const float* bv = Lb + (size_t)s*1600;
    for (int i = tid; i < 1536; i += 512){
      int kf = i >> 9, q = i & 511, l = q >> 3, j = q & 7;
      int k = kf*16 + ((l >> 5) << 3) + j;
      int c = l & 31;
      int d = 4*tt + (c >> 3);
      int e = 32 + (c & 7);
      int n = d*DD + e;
      float v = 0.f;
      if (k < DD) v = W[n*DD + k];
      else if (k == DD) v = bv[n];
      dst[i] = f2bf(v);
    }
  } else if (bid < 459){                // Qw (+Eb+Qb at k=40, Ew at k=41)
    int s = bid - 450;
    unsigned short* dst = ws + WS_QW + (size_t)s*3072;
    const float* W = Qw + (size_t)s*1600;
    for (int i = tid; i < 3072; i += 512){
      int et = i / 1536, r = i - et*1536;
      int kf = r >> 9, q = r & 511, l = q >> 3, j = q & 7;
      int k = kf*16 + ((l >> 5) << 3) + j;
      int jc = et*32 + (l & 31);
      float v = 0.f;
      if (jc < DD){
        if (k < DD) v = W[jc*DD + k];
        else if (k == DD) v = Eb[s*DD + jc] + Qb[s*DD + jc];
        else if (k == DD+1) v = Ew[s*DD + jc];
      }
      dst[i] = f2bf(v);
    }
  } else if (bid < 468){                // Mw 16x16 B-frags (+Mb at k=40)  [r18]
    int s = bid - 459;
    unsigned short* dst = ws + WS_MW + (size_t)s*3072;
    const float* W = Mw + (size_t)s*1600;
    for (int i = tid; i < 3072; i += 512){
      int et = i >> 10, r = i & 1023, kf = r >> 9, q = r & 511, l = q >> 3, j = q & 7;
      int k = kf*32 + ((l >> 4) << 3) + j;
      int e = et*16 + (l & 15);
      float v = 0.f;
      if (e < DD){
        if (k < DD) v = W[e*DD + k];
        else if (k == DD) v = Mb[s*DD + e];
      }
      dst[i] = f2bf(v);
    }
  } else {                              // Tw (+Tb at k=40)
    int t = bid - 468;
    unsigned short* dst = ws + WS_TW + (size_t)t*1536;
    for (int i = tid; i < 1536; i += 512){
      int kf = i >> 9, q = i & 511, l = q >> 3, j = q & 7;
      int k = kf*16 + ((l >> 5) << 3) + j;
      int a = t*32 + (l & 31);
      float v = 0.f;
      if (a < ANUM){
        if (k < DD) v = Tw[(size_t)a*DD + k];
        else if (k == DD) v = Tb[a];
      }
      dst[i] = f2bf(v);
    }
  }
}

// r17 base (best). r18 deltas:
//  - C(s) on 6 waves via 16x16x32 MFMA (ae/Mw in 16-order): per-lane red-sum
//    drops 128 -> 32 scalar reads, spread 3x wider (phase 2 was the remaining
//    2-wave serialized segment).
//  - red stride 42 (<=2-way banks for all access groups).
//  - s_setprio(1) around B's MFMA/contraction core (role diversity exists).
//  - final h -> pbuf[0] (dead p1(7) storage; bias slots preserved).
__global__ __launch_bounds__(512)
void star_main(const int* __restrict__ X,
               const int* __restrict__ T1,
               const int* __restrict__ T2,
               const float* __restrict__ emb,
               const unsigned short* __restrict__ ws,
               float* __restrict__ out)
{
  __shared__ __align__(16) unsigned short pbuf[2][3072];  // p-state, 32x32 A-frag order
  __shared__ __align__(16) unsigned short aebf16[2][2048];// emb gather, 16x16 A-frag order
  __shared__ __align__(16) float hT[2][DD*36];            // h-state, [d][m]
  __shared__ __align__(16) float red[8][MB*RST2];         // tt partials per wave
  __shared__ int   aeidx[SLM1][MB];
  __shared__ float tvtab[SLM1][MB];

  const int tid = threadIdx.x;
  const int w = __builtin_amdgcn_readfirstlane(tid >> 6);
  const int l = tid & 63;
  const int col = l & 31, half = l >> 5;
  const int row0 = blockIdx.x * MB;

  // ---- prologue ----
  {
    unsigned int* p = (unsigned int*)&pbuf[0][0];
    for (int i = tid; i < 3072; i += 512) p[i] = 0u;
    unsigned int* a = (unsigned int*)&aebf16[0][0];
    for (int i = tid; i < 2048; i += 512) a[i] = 0u;
    float* rr = &red[0][0];
    for (int i = tid; i < 8*MB*RST2; i += 512) rr[i] = 0.f;  // C(0) sums zeros
  }
  if (tid < MB*SLM1){
    int m = tid / SLM1, s = tid - m*SLM1;
    int r = row0 + m;
    aeidx[s][m] = X[(size_t)r*40 + s*4 + 3];
    tvtab[s][m] = (float)(T1[r*SLM1 + s]*8 + T2[r*SLM1 + s]);
  }
  __syncthreads();
  if (tid < MB){
    int off = 2*1024 + (tid + 32)*8;    // p-state: k=40 bias mult, k=41 tvec
    pbuf[0][off] = 0x3F80; pbuf[1][off] = 0x3F80;
    pbuf[0][off+1] = f2bf(tvtab[0][tid]);
    pbuf[1][off+1] = f2bf(tvtab[1][tid]);
    // ae 16-order bias: k=40 -> kf=1,kk=8
    int o16 = ae16_off(tid, 40);
    aebf16[0][o16] = 0x3F80; aebf16[1][o16] = 0x3F80;
  }
  if (tid < 320){  // gather ae(0), 16-order
    int m = tid / 10, q4 = tid - m*10;
    float4 v4 = *(const float4*)(emb + (size_t)aeidx[0][m]*DD + q4*4);
    #pragma unroll
    for (int c2 = 0; c2 < 4; ++c2)
      aebf16[0][ae16_off(m, q4*4 + c2)] = f2bf(((const float*)&v4)[c2]);
  }
  __syncthreads();
  // A(0): p1(0) = relu6(0@Qw + t*Ew + Eb + Qb), waves 0,1
  if (w < 2){
    short8 a0 = ((const short8*)&pbuf[0][0])[l];
    short8 a1 = ((const short8*)&pbuf[0][1024])[l];
    short8 a2 = ((const short8*)&pbuf[0][2048])[l];
    const unsigned short* qwb = ws + WS_QW + w*1536;
    f32x16 c = mfma3(a0, a1, a2, ((const short8*)qwb)[l],
                     ((const short8*)(qwb+512))[l], ((const short8*)(qwb+1024))[l]);
    int j = w*32 + col;
    if (j < DD){
      int kf = j >> 4, kk = j & 15;
      #pragma unroll
      for (int r = 0; r < 16; ++r){
        int m = (r & 3) + ((r >> 2) << 3) + (half << 2);
        pbuf[1][kf*1024 + (m + ((kk >> 3) << 5))*8 + (kk & 7)] = f2bf(relu6f(c[r]));
      }
    }
  }
  __syncthreads();

  // cross-step prefetch regs: next step's first pair (d = w, d = w+8)
  short8 q00, q01, q02, q10, q11, q12;

  for (int s = 0; s < SLM1; ++s){
    const int pcur = (s + 1) & 1;   // buffer holding p1(s)
    const int hrd  = s & 1;

    // ---- phase 1: B(s) (all waves, dual-stream) + A(s+1) (waves 6,7) ----
    float4 gv; int gm = 0, gq = 0;
    const bool dog = (s < 8) && (tid < 320);
    if (dog){
      gm = tid / 10; gq = tid - gm*10;
      gv = *(const float4*)(emb + (size_t)aeidx[s+1][gm]*DD + gq*4);
    }
    short8 pa0 = ((const short8*)&pbuf[pcur][0])[l];
    short8 pa1 = ((const short8*)&pbuf[pcur][1024])[l];
    short8 pa2 = ((const short8*)&pbuf[pcur][2048])[l];

    // stream regs; after the main loop B* carries the tail / Qw triplet
    short8 A0, A1, A2, B0, B1, B2;

    if (s > 0){
      const float* hbase = &hT[hrd][half << 2];
      const unsigned short* lwf = ws + WS_LWF + (size_t)(s*40)*1536;

      A0 = q00; A1 = q01; A2 = q02;    // d = w      (cross-step prefetch)
      B0 = q10; B1 = q11; B2 = q12;    // d = w+8
      f32x16 tt = {0,0,0,0,0,0,0,0,0,0,0,0,0,0,0,0};

      __builtin_amdgcn_s_setprio(1);
      #pragma unroll
      for (int it = 0; it < 2; ++it){
        // prefetch next pair (it0: d=w+16,w+24 ; it1: d=w+32 + tail/Qw triplet)
        short8 NA0, NA1, NA2, NB0, NB1, NB2;
        if (it == 0){
          const unsigned short* fA = lwf + (size_t)(16 + w)*1536;
          NA0 = ((const short8*)fA)[l];
          NA1 = ((const short8*)(fA + 512))[l];
          NA2 = ((const short8*)(fA + 1024))[l];
          const unsigned short* fB = lwf + (size_t)(24 + w)*1536;
          NB0 = ((const short8*)fB)[l];
          NB1 = ((const short8*)(fB + 512))[l];
          NB2 = ((const short8*)(fB + 1024))[l];
        } else {
          const unsigned short* fA = lwf + (size_t)(32 + w)*1536;
          NA0 = ((const short8*)fA)[l];
          NA1 = ((const short8*)(fA + 512))[l];
          NA2 = ((const short8*)(fA + 1024))[l];
          const size_t qs = (s < 8) ? (size_t)(s + 1) : (size_t)8;
          const unsigned short* fB = (w < 6)
              ? ws + WS_LWT + (size_t)(s*10 + w)*1536
              : ws + WS_QW + qs*3072 + (size_t)(w - 6)*1536;
          NB0 = ((const short8*)fB)[l];
          NB1 = ((const short8*)(fB + 512))[l];
          NB2 = ((const short8*)(fB + 1024))[l];
        }
        // two independent MFMA chains, interleaved
        f32x16 ca = {0,0,0,0,0,0,0,0,0,0,0,0,0,0,0,0};
        f32x16 cb = {0,0,0,0,0,0,0,0,0,0,0,0,0,0,0,0};
        ca = __builtin_amdgcn_mfma_f32_32x32x16_bf16(pa0, A0, ca, 0, 0, 0);
        cb = __builtin_amdgcn_mfma_f32_32x32x16_bf16(pa0, B0, cb, 0, 0, 0);
        ca = __builtin_amdgcn_mfma_f32_32x32x16_bf16(pa1, A1, ca, 0, 0, 0);
        cb = __builtin_amdgcn_mfma_f32_32x32x16_bf16(pa1, B1, cb, 0, 0, 0);
        ca = __builtin_amdgcn_mfma_f32_32x32x16_bf16(pa2, A2, ca, 0, 0, 0);
        cb = __builtin_amdgcn_mfma_f32_32x32x16_bf16(pa2, B2, cb, 0, 0, 0);
        // contraction for both d's, one f32x4 of h per stream live
        const int dA = it*16 + w, dB = it*16 + 8 + w;
        const float* hA = hbase + dA*36;
        const float* hB = hbase + dB*36;
        #pragma unroll
        for (int g = 0; g < 4; ++g){
          f32x4 ha = *(const f32x4*)(hA + g*8);
          f32x4 hb = *(const f32x4*)(hB + g*8);
          #pragma unroll
          for (int q = 0; q < 4; ++q){
            tt[g*4+q] = fmaf(ha[q], relu6f(ca[g*4+q]), tt[g*4+q]);
            tt[g*4+q] = fmaf(hb[q], relu6f(cb[g*4+q]), tt[g*4+q]);
          }
        }
        A0 = NA0; A1 = NA1; A2 = NA2;
        B0 = NB0; B1 = NB1; B2 = NB2;
      }
      // single stream: d = w+32 (in A regs)
      {
        f32x16 c = mfma3(pa0, pa1, pa2, A0, A1, A2);
        const float* hb = hbase + (32 + w)*36;
        #pragma unroll
        for (int g = 0; g < 4; ++g){
          f32x4 hg = *(const f32x4*)(hb + g*8);
          #pragma unroll
          for (int q = 0; q < 4; ++q)
            tt[g*4+q] = fmaf(hg[q], relu6f(c[g*4+q]), tt[g*4+q]);
        }
      }
      __builtin_amdgcn_s_setprio(0);
      // commit full-tile partials (plain stores, per-wave slice)
      #pragma unroll
      for (int r = 0; r < 16; ++r){
        int m = (r & 3) + ((r >> 2) << 3) + (half << 2);
        red[w][m*RST2 + col] = tt[r];
      }
    }

    // cross-step prefetch for step s+1 (first pair)
    if (s < 8){
      const unsigned short* nl = ws + WS_LWF + (size_t)((s+1)*40)*1536;
      const unsigned short* n0 = nl + (size_t)w*1536;
      q00 = ((const short8*)n0)[l];
      q01 = ((const short8*)(n0 + 512))[l];
      q02 = ((const short8*)(n0 + 1024))[l];
      const unsigned short* n1 = nl + (size_t)(8 + w)*1536;
      q10 = ((const short8*)n1)[l];
      q11 = ((const short8*)(n1 + 512))[l];
      q12 = ((const short8*)(n1 + 1024))[l];
    }

    if (s > 0 && w < 6){
      // packed tails, waves 0-5 stride 6; first tile's triplet in B regs
      const unsigned short* lwt = ws + WS_LWT + (size_t)(s*10)*1536;
      f32x16 tacc = {0,0,0,0,0,0,0,0,0,0,0,0,0,0,0,0};
      {
        f32x16 c = mfma3(pa0, pa1, pa2, B0, B1, B2);
        int dt = 4*w + (col >> 3);
        const float* hb0 = &hT[hrd][dt*36 + (half << 2)];
        #pragma unroll
        for (int g = 0; g < 4; ++g){
          f32x4 hg = *(const f32x4*)(hb0 + g*8);
          #pragma unroll
          for (int q = 0; q < 4; ++q){
            float val = hg[q]*relu6f(c[g*4+q]);
            val += __shfl_xor(val, 8);
            val += __shfl_xor(val, 16);
            tacc[g*4+q] += val;
          }
        }
      }
      if (w < 4){
        const int t2 = w + 6;
        const unsigned short* ft = lwt + (size_t)t2*1536;
        short8 t0 = ((const short8*)ft)[l];
        short8 t1 = ((const short8*)(ft + 512))[l];
        short8 t2r = ((const short8*)(ft + 1024))[l];
        f32x16 c = mfma3(pa0, pa1, pa2, t0, t1, t2r);
        int dt = 4*t2 + (col >> 3);
        const float* hb = &hT[hrd][dt*36 + (half << 2)];
        #pragma unroll
        for (int g = 0; g < 4; ++g){
          f32x4 hg = *(const f32x4*)(hb + g*8);
          #pragma unroll
          for (int q = 0; q < 4; ++q){
            float val = hg[q]*relu6f(c[g*4+q]);
            val += __shfl_xor(val, 8);
            val += __shfl_xor(val, 16);
            tacc[g*4+q] += val;
          }
        }
      }
      if (col < 8){
        #pragma unroll
        for (int r = 0; r < 16; ++r){
          int m = (r & 3) + ((r >> 2) << 3) + (half << 2);
          red[w][m*RST2 + 32 + col] = tacc[r];
        }
      }
    } else if (w >= 6 && s < 8){
      // A(s+1) on waves 6,7: Qw triplet in B regs (s>0) or loaded inline (s==0)
      short8 Q0, Q1, Q2;
      if (s == 0){
        const unsigned short* qwb = ws + WS_QW + (size_t)(s+1)*3072 + (size_t)(w-6)*1536;
        Q0 = ((const short8*)qwb)[l];
        Q1 = ((const short8*)(qwb + 512))[l];
        Q2 = ((const short8*)(qwb + 1024))[l];
      } else {
        Q0 = B0; Q1 = B1; Q2 = B2;
      }
      f32x16 c = mfma3(pa0, pa1, pa2, Q0, Q1, Q2);
      int j = (w - 6)*32 + col;
      if (j < DD){
        int kf = j >> 4, kk = j & 15;
        #pragma unroll
        for (int r = 0; r < 16; ++r){
          int m = (r & 3) + ((r >> 2) << 3) + (half << 2);
          pbuf[s & 1][kf*1024 + (m + ((kk >> 3) << 5))*8 + (kk & 7)] = f2bf(relu6f(c[r]));
        }
      }
    }
    // late writes: ae(s+1) 16-order; tvec(s+2) into pbuf[s&1] k=41 slot
    if (dog){
      unsigned short* dst = &aebf16[(s+1) & 1][0];
      #pragma unroll
      for (int c2 = 0; c2 < 4; ++c2)
        dst[ae16_off(gm, gq*4 + c2)] = f2bf(((const float*)&gv)[c2]);
    }
    if (s <= 6 && tid < MB)
      pbuf[s & 1][2*1024 + (tid + 32)*8 + 1] = f2bf(tvtab[s+2][tid]);
    __syncthreads();

    // ---- phase 2: C(s) on 6 waves via 16x16x32 MFMA ----
    if (w < 6){
      const int mt = (w >= 3) ? 1 : 0, et = w - mt*3;
      const int lr = l & 15, lg = l >> 4;
      const int e = et*16 + lr;
      const int mbase = mt*16 + (lg << 2);
      f32x4 c = {0.f, 0.f, 0.f, 0.f};
      if (e < DD){
        #pragma unroll
        for (int r = 0; r < 4; ++r){
          int m = mbase + r;
          float acc = red[0][m*RST2 + e];
          #pragma unroll
          for (int dp = 1; dp < 8; ++dp) acc += red[dp][m*RST2 + e];
          c[r] = acc;
        }
      }
      const unsigned short* ab = &aebf16[s & 1][mt*1024];
      short8 a0 = ((const short8*)ab)[l];
      short8 a1 = ((const short8*)(ab + 512))[l];
      const unsigned short* mwb = ws + WS_MW + (size_t)s*3072 + (size_t)et*1024;
      short8 b0 = ((const short8*)mwb)[l];
      short8 b1 = ((const short8*)(mwb + 512))[l];
      c = __builtin_amdgcn_mfma_f32_16x16x32_bf16(a0, b0, c, 0, 0, 0);
      c = __builtin_amdgcn_mfma_f32_16x16x32_bf16(a1, b1, c, 0, 0, 0);
      if (e < DD){
        #pragma unroll
        for (int r = 0; r < 4; ++r){
          int m = mbase + r;
          float v = relu6f(c[r]);
          hT[(s+1) & 1][e*36 + m] = v;
          if (s == SLM1-1){
            int kf = e >> 4, kk = e & 15;   // final h -> pbuf[0] (dead p1(7))
            pbuf[0][kf*1024 + (m + ((kk >> 3) << 5))*8 + (kk & 7)] = f2bf(v);
          }
        }
      }
    }
    __syncthreads();
  }

  // ---- epilogue: out = h@Tw^T + Tb via MFMA (h-frag in pbuf[0]) ----
  for (int t = w; t < 9; t += 8){
    short8 a0 = ((const short8*)&pbuf[0][0])[l];
    short8 a1 = ((const short8*)&pbuf[0][1024])[l];
    short8 a2 = ((const short8*)&pbuf[0][2048])[l];
    const unsigned short* twb = ws + WS_TW + (size_t)t*1536;
    f32x16 c = mfma3(a0, a1, a2, ((const short8*)twb)[l],
                     ((const short8*)(twb+512))[l], ((const short8*)(twb+1024))[l]);
    int a = t*32 + col;
    if (a < ANUM){
      #pragma unroll
      for (int r = 0; r < 16; ++r){
        int m = (r & 3) + ((r >> 2) << 3) + (half << 2);
        out[(size_t)(row0 + m)*ANUM + a] = c[r];
      }
    }
  }
}

extern "C" void kernel_launch(void* const* d_in, const int* in_sizes, int n_in,
                              void* d_out, int out_size, void* d_ws, size_t ws_size,
                              hipStream_t stream) {
  const int*   X  = (const int*)  d_in[0];
  const int*   T1 = (const int*)  d_in[1];
  const int*   T2 = (const int*)  d_in[2];
  const float* Ew = (const float*)d_in[3];
  const float* Eb = (const float*)d_in[4];
  const float* Qw = (const float*)d_in[5];
  const float* Qb = (const float*)d_in[6];
  const float* Lw = (const float*)d_in[7];
  const float* Lb = (const float*)d_in[8];
  const float* Mw = (const float*)d_in[9];
  const float* Mb = (const float*)d_in[10];
  const float* Tw = (const float*)d_in[11];
  const float* Tb = (const float*)d_in[12];
  const float* em = (const float*)d_in[13];
  unsigned short* ws = (unsigned short*)d_ws;
  float* out = (float*)d_out;

  prep_frags<<<dim3(477), dim3(512), 0, stream>>>(Qw, Lw, Mw, Tw, Ew, Eb, Qb,
                                                  Lb, Mb, Tb, ws);
  star_main<<<dim3(8192 / MB), dim3(512), 0, stream>>>(X, T1, T2, em, ws, out);
}

// Round 19
// 48.448 us; speedup vs baseline: 1.4410x; 1.0019x over previous
//
#include <hip/hip_runtime.h>

#define DD 40
#define SLM1 9
#define ANUM 268
#define MB 32
#define RST2 42   // red row stride (f32): all access groups <=2-way on banks

typedef __attribute__((ext_vector_type(8))) short short8;
typedef __attribute__((ext_vector_type(4))) float f32x4;
typedef __attribute__((ext_vector_type(16))) float f32x16;

// ws offsets (u16 units)
#define WS_LWF ((size_t)0)        // full tiles: (s*40+d)*1536 ; e=0..31 (32x32 B-frag)
#define WS_LWT ((size_t)552960)   // tail tiles: (s*10+t)*1536 ; col c -> d=4t+(c>>3), e=32+(c&7)
#define WS_QW  ((size_t)691200)   // s*3072 (+ et*1536)   (32x32 B-frag)
#define WS_MW  ((size_t)718848)   // s*3072 + et*1024 + kf*512  (16x16 B-frag)
#define WS_TW  ((size_t)746496)   // t*1536               (32x32 B-frag)

__device__ __forceinline__ unsigned short f2bf(float f){
  unsigned int u = __float_as_uint(f);
  u += 0x7FFFu + ((u >> 16) & 1u);
  return (unsigned short)(u >> 16);
}
__device__ __forceinline__ float relu6f(float v){
  return fminf(fmaxf(v, 0.0f), 6.0f);
}

__device__ __forceinline__ f32x16 mfma3(short8 a0, short8 a1, short8 a2,
                                        short8 b0, short8 b1, short8 b2){
  f32x16 c = {0,0,0,0,0,0,0,0,0,0,0,0,0,0,0,0};
  c = __builtin_amdgcn_mfma_f32_32x32x16_bf16(a0, b0, c, 0, 0, 0);
  c = __builtin_amdgcn_mfma_f32_32x32x16_bf16(a1, b1, c, 0, 0, 0);
  c = __builtin_amdgcn_mfma_f32_32x32x16_bf16(a2, b2, c, 0, 0, 0);
  return c;
}

// ae 16x16 A-frag offset for element (m,k): lane = ((k&31)>>3)*16 + (m&15)
__device__ __forceinline__ int ae16_off(int m, int k){
  return (m >> 4)*1024 + (k >> 5)*512 + (((k & 31) >> 3) << 7) + (m & 15)*8 + (k & 7);
}

// 32x32 B-frag: col = l&31, k = 8*(l>>5)+j (+16*kf)   (verified r3-r18)
// 16x16 B-frag: col = l&15, k = 8*(l>>4)+j (+32*kf)   (verified r2/r13/r18)
__global__ __launch_bounds__(512)
void prep_frags(const float* __restrict__ Qw, const float* __restrict__ Lw,
                const float* __restrict__ Mw, const float* __restrict__ Tw,
                const float* __restrict__ Ew, const float* __restrict__ Eb,
                const float* __restrict__ Qb, const float* __restrict__ Lb,
                const float* __restrict__ Mb, const float* __restrict__ Tb,
                unsigned short* __restrict__ ws)
{
  const int bid = blockIdx.x, tid = threadIdx.x;
  if (bid < 360){                       // Lw full tiles (e 0..31), one per (s,d)
    int s = bid / 40, d = bid - s*40;
    unsigned short* dst = ws + WS_LWF + (size_t)bid*1536;
    const float* W = Lw + (size_t)s*64000;
    const float* bv = Lb + (size_t)s*1600;
    for (int i = tid; i < 1536; i += 512){
      int kf = i >> 9, q = i & 511, l = q >> 3, j = q & 7;
      int k = kf*16 + ((l >> 5) << 3) + j;
      int e = l & 31;
      int n = d*DD + e;
      float v = 0.f;
      if (k < DD) v = W[n*DD + k];
      else if (k == DD) v = bv[n];
      dst[i] = f2bf(v);
    }
  } else if (bid < 450){                // Lw tail tiles (e 32..39, 4 d's packed)
    int t = bid - 360;
    int s = t / 10, tt = t - s*10;
    unsigned short* dst = ws + WS_LWT + (size_t)t*1536;
    const float* W = Lw + (size_t)s*64000;
    const float* bv = Lb + (size_t)s*1600;
    for (int i = tid; i < 1536; i += 512){
      int kf = i >> 9, q = i & 511, l = q >> 3, j = q & 7;
      int k = kf*16 + ((l >> 5) << 3) + j;
      int c = l & 31;
      int d = 4*tt + (c >> 3);
      int e = 32 + (c & 7);
      int n = d*DD + e;
      float v = 0.f;
      if (k < DD) v = W[n*DD + k];
      else if (k == DD) v = bv[n];
      dst[i] = f2bf(v);
    }
  } else if (bid < 459){                // Qw (+Eb+Qb at k=40, Ew at k=41)
    int s = bid - 450;
    unsigned short* dst = ws + WS_QW + (size_t)s*3072;
    const float* W = Qw + (size_t)s*1600;
    for (int i = tid; i < 3072; i += 512){
      int et = i / 1536, r = i - et*1536;
      int kf = r >> 9, q = r & 511, l = q >> 3, j = q & 7;
      int k = kf*16 + ((l >> 5) << 3) + j;
      int jc = et*32 + (l & 31);
      float v = 0.f;
      if (jc < DD){
        if (k < DD) v = W[jc*DD + k];
        else if (k == DD) v = Eb[s*DD + jc] + Qb[s*DD + jc];
        else if (k == DD+1) v = Ew[s*DD + jc];
      }
      dst[i] = f2bf(v);
    }
  } else if (bid < 468){                // Mw 16x16 B-frags (+Mb at k=40)
    int s = bid - 459;
    unsigned short* dst = ws + WS_MW + (size_t)s*3072;
    const float* W = Mw + (size_t)s*1600;
    for (int i = tid; i < 3072; i += 512){
      int et = i >> 10, r = i & 1023, kf = r >> 9, q = r & 511, l = q >> 3, j = q & 7;
      int k = kf*32 + ((l >> 4) << 3) + j;
      int e = et*16 + (l & 15);
      float v = 0.f;
      if (e < DD){
        if (k < DD) v = W[e*DD + k];
        else if (k == DD) v = Mb[s*DD + e];
      }
      dst[i] = f2bf(v);
    }
  } else {                              // Tw (+Tb at k=40)
    int t = bid - 468;
    unsigned short* dst = ws + WS_TW + (size_t)t*1536;
    for (int i = tid; i < 1536; i += 512){
      int kf = i >> 9, q = i & 511, l = q >> 3, j = q & 7;
      int k = kf*16 + ((l >> 5) << 3) + j;
      int a = t*32 + (l & 31);
      float v = 0.f;
      if (a < ANUM){
        if (k < DD) v = Tw[(size_t)a*DD + k];
        else if (k == DD) v = Tb[a];
      }
      dst[i] = f2bf(v);
    }
  }
}

// r18 base (best, 48.5us). r19 deltas:
//  - cross-step prefetch deepened to BOTH pairs (4 triplets, 48 persistent
//    VGPRs; r18 left 48 regs of headroom at VGPR=80). single+tail triplets
//    issue at B start, hidden under pair0+pair1 compute -> no L2 load on
//    B's critical path at depth <2.
//  - C's hT store vectorized to one f32x4 (m-contiguous, 16B-aligned):
//    r18's scalar stride-36 stores were an 8-way bank conflict on 6 waves
//    (conflicts 687K -> 1.49M).
__global__ __launch_bounds__(512)
void star_main(const int* __restrict__ X,
               const int* __restrict__ T1,
               const int* __restrict__ T2,
               const float* __restrict__ emb,
               const unsigned short* __restrict__ ws,
               float* __restrict__ out)
{
  __shared__ __align__(16) unsigned short pbuf[2][3072];  // p-state, 32x32 A-frag order
  __shared__ __align__(16) unsigned short aebf16[2][2048];// emb gather, 16x16 A-frag order
  __shared__ __align__(16) float hT[2][DD*36];            // h-state, [d][m]
  __shared__ __align__(16) float red[8][MB*RST2];         // tt partials per wave
  __shared__ int   aeidx[SLM1][MB];
  __shared__ float tvtab[SLM1][MB];

  const int tid = threadIdx.x;
  const int w = __builtin_amdgcn_readfirstlane(tid >> 6);
  const int l = tid & 63;
  const int col = l & 31, half = l >> 5;
  const int row0 = blockIdx.x * MB;

  // ---- prologue ----
  {
    unsigned int* p = (unsigned int*)&pbuf[0][0];
    for (int i = tid; i < 3072; i += 512) p[i] = 0u;
    unsigned int* a = (unsigned int*)&aebf16[0][0];
    for (int i = tid; i < 2048; i += 512) a[i] = 0u;
    float* rr = &red[0][0];
    for (int i = tid; i < 8*MB*RST2; i += 512) rr[i] = 0.f;  // C(0) sums zeros
  }
  if (tid < MB*SLM1){
    int m = tid / SLM1, s = tid - m*SLM1;
    int r = row0 + m;
    aeidx[s][m] = X[(size_t)r*40 + s*4 + 3];
    tvtab[s][m] = (float)(T1[r*SLM1 + s]*8 + T2[r*SLM1 + s]);
  }
  __syncthreads();
  if (tid < MB){
    int off = 2*1024 + (tid + 32)*8;    // p-state: k=40 bias mult, k=41 tvec
    pbuf[0][off] = 0x3F80; pbuf[1][off] = 0x3F80;
    pbuf[0][off+1] = f2bf(tvtab[0][tid]);
    pbuf[1][off+1] = f2bf(tvtab[1][tid]);
    int o16 = ae16_off(tid, 40);        // ae 16-order bias
    aebf16[0][o16] = 0x3F80; aebf16[1][o16] = 0x3F80;
  }
  if (tid < 320){  // gather ae(0), 16-order
    int m = tid / 10, q4 = tid - m*10;
    float4 v4 = *(const float4*)(emb + (size_t)aeidx[0][m]*DD + q4*4);
    #pragma unroll
    for (int c2 = 0; c2 < 4; ++c2)
      aebf16[0][ae16_off(m, q4*4 + c2)] = f2bf(((const float*)&v4)[c2]);
  }
  __syncthreads();
  // A(0): p1(0) = relu6(0@Qw + t*Ew + Eb + Qb), waves 0,1
  if (w < 2){
    short8 a0 = ((const short8*)&pbuf[0][0])[l];
    short8 a1 = ((const short8*)&pbuf[0][1024])[l];
    short8 a2 = ((const short8*)&pbuf[0][2048])[l];
    const unsigned short* qwb = ws + WS_QW + w*1536;
    f32x16 c = mfma3(a0, a1, a2, ((const short8*)qwb)[l],
                     ((const short8*)(qwb+512))[l], ((const short8*)(qwb+1024))[l]);
    int j = w*32 + col;
    if (j < DD){
      int kf = j >> 4, kk = j & 15;
      #pragma unroll
      for (int r = 0; r < 16; ++r){
        int m = (r & 3) + ((r >> 2) << 3) + (half << 2);
        pbuf[1][kf*1024 + (m + ((kk >> 3) << 5))*8 + (kk & 7)] = f2bf(relu6f(c[r]));
      }
    }
  }
  __syncthreads();

  // cross-step prefetch regs: next step's BOTH pairs (d = w, w+8, w+16, w+24)
  short8 q00, q01, q02, q10, q11, q12;
  short8 r00, r01, r02, r10, r11, r12;

  for (int s = 0; s < SLM1; ++s){
    const int pcur = (s + 1) & 1;   // buffer holding p1(s)
    const int hrd  = s & 1;

    // ---- phase 1: B(s) (all waves, dual-stream) + A(s+1) (waves 6,7) ----
    float4 gv; int gm = 0, gq = 0;
    const bool dog = (s < 8) && (tid < 320);
    if (dog){
      gm = tid / 10; gq = tid - gm*10;
      gv = *(const float4*)(emb + (size_t)aeidx[s+1][gm]*DD + gq*4);
    }
    short8 pa0 = ((const short8*)&pbuf[pcur][0])[l];
    short8 pa1 = ((const short8*)&pbuf[pcur][1024])[l];
    short8 pa2 = ((const short8*)&pbuf[pcur][2048])[l];

    // T regs carry the tail / Qw triplet into the post-B sections
    short8 T0, T1r, T2r;

    if (s > 0){
      const float* hbase = &hT[hrd][half << 2];
      const unsigned short* lwf = ws + WS_LWF + (size_t)(s*40)*1536;

      // issue single (d=w+32) + tail/Qw loads NOW (hide under 2 pairs' compute)
      short8 S0, S1, S2;
      {
        const unsigned short* fS = lwf + (size_t)(32 + w)*1536;
        S0 = ((const short8*)fS)[l];
        S1 = ((const short8*)(fS + 512))[l];
        S2 = ((const short8*)(fS + 1024))[l];
        const size_t qs = (s < 8) ? (size_t)(s + 1) : (size_t)8;
        const unsigned short* fT = (w < 6)
            ? ws + WS_LWT + (size_t)(s*10 + w)*1536
            : ws + WS_QW + qs*3072 + (size_t)(w - 6)*1536;
        T0  = ((const short8*)fT)[l];
        T1r = ((const short8*)(fT + 512))[l];
        T2r = ((const short8*)(fT + 1024))[l];
      }

      f32x16 tt = {0,0,0,0,0,0,0,0,0,0,0,0,0,0,0,0};
      __builtin_amdgcn_s_setprio(1);
      // pair 0 (d = w, w+8) -- fragments prefetched LAST step
      {
        f32x16 ca = {0,0,0,0,0,0,0,0,0,0,0,0,0,0,0,0};
        f32x16 cb = {0,0,0,0,0,0,0,0,0,0,0,0,0,0,0,0};
        ca = __builtin_amdgcn_mfma_f32_32x32x16_bf16(pa0, q00, ca, 0, 0, 0);
        cb = __builtin_amdgcn_mfma_f32_32x32x16_bf16(pa0, q10, cb, 0, 0, 0);
        ca = __builtin_amdgcn_mfma_f32_32x32x16_bf16(pa1, q01, ca, 0, 0, 0);
        cb = __builtin_amdgcn_mfma_f32_32x32x16_bf16(pa1, q11, cb, 0, 0, 0);
        ca = __builtin_amdgcn_mfma_f32_32x32x16_bf16(pa2, q02, ca, 0, 0, 0);
        cb = __builtin_amdgcn_mfma_f32_32x32x16_bf16(pa2, q12, cb, 0, 0, 0);
        const float* hA = hbase + (w)*36;
        const float* hB = hbase + (8 + w)*36;
        #pragma unroll
        for (int g = 0; g < 4; ++g){
          f32x4 ha = *(const f32x4*)(hA + g*8);
          f32x4 hb = *(const f32x4*)(hB + g*8);
          #pragma unroll
          for (int q = 0; q < 4; ++q){
            tt[g*4+q] = fmaf(ha[q], relu6f(ca[g*4+q]), tt[g*4+q]);
            tt[g*4+q] = fmaf(hb[q], relu6f(cb[g*4+q]), tt[g*4+q]);
          }
        }
      }
      // pair 1 (d = w+16, w+24) -- also prefetched last step
      {
        f32x16 ca = {0,0,0,0,0,0,0,0,0,0,0,0,0,0,0,0};
        f32x16 cb = {0,0,0,0,0,0,0,0,0,0,0,0,0,0,0,0};
        ca = __builtin_amdgcn_mfma_f32_32x32x16_bf16(pa0, r00, ca, 0, 0, 0);
        cb = __builtin_amdgcn_mfma_f32_32x32x16_bf16(pa0, r10, cb, 0, 0, 0);
        ca = __builtin_amdgcn_mfma_f32_32x32x16_bf16(pa1, r01, ca, 0, 0, 0);
        cb = __builtin_amdgcn_mfma_f32_32x32x16_bf16(pa1, r11, cb, 0, 0, 0);
        ca = __builtin_amdgcn_mfma_f32_32x32x16_bf16(pa2, r02, ca, 0, 0, 0);
        cb = __builtin_amdgcn_mfma_f32_32x32x16_bf16(pa2, r12, cb, 0, 0, 0);
        const float* hA = hbase + (16 + w)*36;
        const float* hB = hbase + (24 + w)*36;
        #pragma unroll
        for (int g = 0; g < 4; ++g){
          f32x4 ha = *(const f32x4*)(hA + g*8);
          f32x4 hb = *(const f32x4*)(hB + g*8);
          #pragma unroll
          for (int q = 0; q < 4; ++q){
            tt[g*4+q] = fmaf(ha[q], relu6f(ca[g*4+q]), tt[g*4+q]);
            tt[g*4+q] = fmaf(hb[q], relu6f(cb[g*4+q]), tt[g*4+q]);
          }
        }
      }
      // single (d = w+32)
      {
        f32x16 c = mfma3(pa0, pa1, pa2, S0, S1, S2);
        const float* hb = hbase + (32 + w)*36;
        #pragma unroll
        for (int g = 0; g < 4; ++g){
          f32x4 hg = *(const f32x4*)(hb + g*8);
          #pragma unroll
          for (int q = 0; q < 4; ++q)
            tt[g*4+q] = fmaf(hg[q], relu6f(c[g*4+q]), tt[g*4+q]);
        }
      }
      __builtin_amdgcn_s_setprio(0);
      // commit full-tile partials (plain stores, per-wave slice)
      #pragma unroll
      for (int r = 0; r < 16; ++r){
        int m = (r & 3) + ((r >> 2) << 3) + (half << 2);
        red[w][m*RST2 + col] = tt[r];
      }
    }

    // cross-step prefetch for step s+1: BOTH pairs (in flight through
    // tails/A + C + barrier -- a >400-cycle window)
    if (s < 8){
      const unsigned short* nl = ws + WS_LWF + (size_t)((s+1)*40)*1536;
      const unsigned short* n0 = nl + (size_t)w*1536;
      q00 = ((const short8*)n0)[l];
      q01 = ((const short8*)(n0 + 512))[l];
      q02 = ((const short8*)(n0 + 1024))[l];
      const unsigned short* n1 = nl + (size_t)(8 + w)*1536;
      q10 = ((const short8*)n1)[l];
      q11 = ((const short8*)(n1 + 512))[l];
      q12 = ((const short8*)(n1 + 1024))[l];
      const unsigned short* n2 = nl + (size_t)(16 + w)*1536;
      r00 = ((const short8*)n2)[l];
      r01 = ((const short8*)(n2 + 512))[l];
      r02 = ((const short8*)(n2 + 1024))[l];
      const unsigned short* n3 = nl + (size_t)(24 + w)*1536;
      r10 = ((const short8*)n3)[l];
      r11 = ((const short8*)(n3 + 512))[l];
      r12 = ((const short8*)(n3 + 1024))[l];
    }

    if (s > 0 && w < 6){
      // packed tails, waves 0-5 stride 6; first tile's triplet in T regs
      const unsigned short* lwt = ws + WS_LWT + (size_t)(s*10)*1536;
      f32x16 tacc = {0,0,0,0,0,0,0,0,0,0,0,0,0,0,0,0};
      {
        f32x16 c = mfma3(pa0, pa1, pa2, T0, T1r, T2r);
        int dt = 4*w + (col >> 3);
        const float* hb0 = &hT[hrd][dt*36 + (half << 2)];
        #pragma unroll
        for (int g = 0; g < 4; ++g){
          f32x4 hg = *(const f32x4*)(hb0 + g*8);
          #pragma unroll
          for (int q = 0; q < 4; ++q){
            float val = hg[q]*relu6f(c[g*4+q]);
            val += __shfl_xor(val, 8);
            val += __shfl_xor(val, 16);
            tacc[g*4+q] += val;
          }
        }
      }
      if (w < 4){
        const int t2 = w + 6;
        const unsigned short* ft = lwt + (size_t)t2*1536;
        short8 t0 = ((const short8*)ft)[l];
        short8 t1 = ((const short8*)(ft + 512))[l];
        short8 t2r = ((const short8*)(ft + 1024))[l];
        f32x16 c = mfma3(pa0, pa1, pa2, t0, t1, t2r);
        int dt = 4*t2 + (col >> 3);
        const float* hb = &hT[hrd][dt*36 + (half << 2)];
        #pragma unroll
        for (int g = 0; g < 4; ++g){
          f32x4 hg = *(const f32x4*)(hb + g*8);
          #pragma unroll
          for (int q = 0; q < 4; ++q){
            float val = hg[q]*relu6f(c[g*4+q]);
            val += __shfl_xor(val, 8);
            val += __shfl_xor(val, 16);
            tacc[g*4+q] += val;
          }
        }
      }
      if (col < 8){
        #pragma unroll
        for (int r = 0; r < 16; ++r){
          int m = (r & 3) + ((r >> 2) << 3) + (half << 2);
          red[w][m*RST2 + 32 + col] = tacc[r];
        }
      }
    } else if (w >= 6 && s < 8){
      // A(s+1) on waves 6,7: Qw triplet in T regs (s>0) or loaded inline (s==0)
      short8 Q0, Q1, Q2;
      if (s == 0){
        const unsigned short* qwb = ws + WS_QW + (size_t)(s+1)*3072 + (size_t)(w-6)*1536;
        Q0 = ((const short8*)qwb)[l];
        Q1 = ((const short8*)(qwb + 512))[l];
        Q2 = ((const short8*)(qwb + 1024))[l];
      } else {
        Q0 = T0; Q1 = T1r; Q2 = T2r;
      }
      f32x16 c = mfma3(pa0, pa1, pa2, Q0, Q1, Q2);
      int j = (w - 6)*32 + col;
      if (j < DD){
        int kf = j >> 4, kk = j & 15;
        #pragma unroll
        for (int r = 0; r < 16; ++r){
          int m = (r & 3) + ((r >> 2) << 3) + (half << 2);
          pbuf[s & 1][kf*1024 + (m + ((kk >> 3) << 5))*8 + (kk & 7)] = f2bf(relu6f(c[r]));
        }
      }
    }
    // late writes: ae(s+1) 16-order; tvec(s+2) into pbuf[s&1] k=41 slot
    if (dog){
      unsigned short* dst = &aebf16[(s+1) & 1][0];
      #pragma unroll
      for (int c2 = 0; c2 < 4; ++c2)
        dst[ae16_off(gm, gq*4 + c2)] = f2bf(((const float*)&gv)[c2]);
    }
    if (s <= 6 && tid < MB)
      pbuf[s & 1][2*1024 + (tid + 32)*8 + 1] = f2bf(tvtab[s+2][tid]);
    __syncthreads();

    // ---- phase 2: C(s) on 6 waves via 16x16x32 MFMA ----
    if (w < 6){
      const int mt = (w >= 3) ? 1 : 0, et = w - mt*3;
      const int lr = l & 15, lg = l >> 4;
      const int e = et*16 + lr;
      const int mbase = mt*16 + (lg << 2);
      f32x4 c = {0.f, 0.f, 0.f, 0.f};
      if (e < DD){
        #pragma unroll
        for (int r = 0; r < 4; ++r){
          int m = mbase + r;
          float acc = red[0][m*RST2 + e];
          #pragma unroll
          for (int dp = 1; dp < 8; ++dp) acc += red[dp][m*RST2 + e];
          c[r] = acc;
        }
      }
      const unsigned short* ab = &aebf16[s & 1][mt*1024];
      short8 a0 = ((const short8*)ab)[l];
      short8 a1 = ((const short8*)(ab + 512))[l];
      const unsigned short* mwb = ws + WS_MW + (size_t)s*3072 + (size_t)et*1024;
      short8 b0 = ((const short8*)mwb)[l];
      short8 b1 = ((const short8*)(mwb + 512))[l];
      c = __builtin_amdgcn_mfma_f32_16x16x32_bf16(a0, b0, c, 0, 0, 0);
      c = __builtin_amdgcn_mfma_f32_16x16x32_bf16(a1, b1, c, 0, 0, 0);
      if (e < DD){
        f32x4 hv;
        #pragma unroll
        for (int r = 0; r < 4; ++r) hv[r] = relu6f(c[r]);
        *(f32x4*)&hT[(s+1) & 1][e*36 + mbase] = hv;   // one b128, m-contiguous
        if (s == SLM1-1){
          #pragma unroll
          for (int r = 0; r < 4; ++r){
            int m = mbase + r;
            int kf = e >> 4, kk = e & 15;   // final h -> pbuf[0] (dead p1(7))
            pbuf[0][kf*1024 + (m + ((kk >> 3) << 5))*8 + (kk & 7)] = f2bf(hv[r]);
          }
        }
      }
    }
    __syncthreads();
  }

  // ---- epilogue: out = h@Tw^T + Tb via MFMA (h-frag in pbuf[0]) ----
  for (int t = w; t < 9; t += 8){
    short8 a0 = ((const short8*)&pbuf[0][0])[l];
    short8 a1 = ((const short8*)&pbuf[0][1024])[l];
    short8 a2 = ((const short8*)&pbuf[0][2048])[l];
    const unsigned short* twb = ws + WS_TW + (size_t)t*1536;
    f32x16 c = mfma3(a0, a1, a2, ((const short8*)twb)[l],
                     ((const short8*)(twb+512))[l], ((const short8*)(twb+1024))[l]);
    int a = t*32 + col;
    if (a < ANUM){
      #pragma unroll
      for (int r = 0; r < 16; ++r){
        int m = (r & 3) + ((r >> 2) << 3) + (half << 2);
        out[(size_t)(row0 + m)*ANUM + a] = c[r];
      }
    }
  }
}

extern "C" void kernel_launch(void* const* d_in, const int* in_sizes, int n_in,
                              void* d_out, int out_size, void* d_ws, size_t ws_size,
                              hipStream_t stream) {
  const int*   X  = (const int*)  d_in[0];
  const int*   T1 = (const int*)  d_in[1];
  const int*   T2 = (const int*)  d_in[2];
  const float* Ew = (const float*)d_in[3];
  const float* Eb = (const float*)d_in[4];
  const float* Qw = (const float*)d_in[5];
  const float* Qb = (const float*)d_in[6];
  const float* Lw = (const float*)d_in[7];
  const float* Lb = (const float*)d_in[8];
  const float* Mw = (const float*)d_in[9];
  const float* Mb = (const float*)d_in[10];
  const float* Tw = (const float*)d_in[11];
  const float* Tb = (const float*)d_in[12];
  const float* em = (const float*)d_in[13];
  unsigned short* ws = (unsigned short*)d_ws;
  float* out = (float*)d_out;

  prep_frags<<<dim3(477), dim3(512), 0, stream>>>(Qw, Lw, Mw, Tw, Ew, Eb, Qb,
                                                  Lb, Mb, Tb, ws);
  star_main<<<dim3(8192 / MB), dim3(512), 0, stream>>>(X, T1, T2, em, ws, out);
}